// Round 8
// baseline (859.638 us; speedup 1.0000x reference)
//
#include <hip/hip_runtime.h>
#include <hip/hip_bf16.h>

#define B_   2
#define C_   64
#define H_   48
#define W_   48
#define N_   (H_*W_)     // 2304
#define NH_  8
#define HD_  8
#define EPS_ 1e-5f
#define S2_  0.125f      // scale^2 = 1/hd
#define LOG2E_ 1.44269504f
#define S_   ((size_t)B_ * C_ * N_)   // 294912 floats per workspace slot

__device__ __forceinline__ float wsum64(float v) {
#pragma unroll
  for (int o = 32; o > 0; o >>= 1) v += __shfl_xor(v, o, 64);
  return v;
}

__device__ __forceinline__ float ln_val(float t, float g, float b) {
  float mu  = wsum64(t) * (1.0f / 64.0f);
  float d   = t - mu;
  float var = wsum64(d * d) * (1.0f / 64.0f);
  return d * rsqrtf(var + EPS_) * g + b;
}

// ---- fused 1x1 pconv + BN + 3x LayerNorm; block = one (b,n) row ----------
// grid B*N, block 64 (lane = channel)
__global__ __launch_bounds__(64) void k_pre(
    const float* __restrict__ x, const float* __restrict__ y,
    const float* __restrict__ pw, const float* __restrict__ pb,
    const float* g, const float* bb, const float* m, const float* v,
    const float* lnxg, const float* lnxb,
    const float* lnyg, const float* lnyb,
    const float* lnzg, const float* lnzb,
    float* __restrict__ xl, float* __restrict__ yl, float* __restrict__ zl) {
  __shared__ float xs[64], ys[64];
  int row = blockIdx.x;            // b*N + n
  int c = threadIdx.x;
  int b = row / N_, n = row % N_;
  float xv = x[(size_t)(b * C_ + c) * N_ + n];
  float yv = y[(size_t)(b * C_ + c) * N_ + n];
  xs[c] = xv; ys[c] = yv;
  __syncthreads();
  const float4* wr  = (const float4*)(pw + (size_t)c * 2 * C_);
  const float4* xs4 = (const float4*)xs;
  const float4* ys4 = (const float4*)ys;
  float acc = pb[c];
#pragma unroll
  for (int t = 0; t < 16; ++t) {
    float4 a = xs4[t], wv = wr[t];
    acc += a.x * wv.x + a.y * wv.y + a.z * wv.z + a.w * wv.w;
  }
#pragma unroll
  for (int t = 0; t < 16; ++t) {
    float4 a = ys4[t], wv = wr[16 + t];
    acc += a.x * wv.x + a.y * wv.y + a.z * wv.z + a.w * wv.w;
  }
  float s  = g[c] * rsqrtf(v[c] + EPS_);
  float sh = bb[c] - m[c] * s;
  float tx = xv * s + sh;
  xl[(size_t)row * C_ + c] = ln_val(tx, lnxg[c], lnxb[c]);
  float ty = yv * s + sh;
  yl[(size_t)row * C_ + c] = ln_val(ty, lnyg[c], lnyb[c]);
  float tz = acc * s + sh;
  zl[(size_t)row * C_ + c] = ln_val(tz, lnzg[c], lnzb[c]);
}

// ------------- fused qv (both branches) + k projection --------------------
// grid (2304, 1, 3), block 256. z=0,1: qv branch z; z=2: kproj (first 1152 blocks)
__global__ void k_qvk(const float* __restrict__ lnb, const float* __restrict__ zl,
                      const float* __restrict__ qvw, const float* __restrict__ qvb,
                      const float* __restrict__ kw, const float* __restrict__ kb,
                      float* __restrict__ qb, float* __restrict__ vb,
                      float* __restrict__ kk) {
  int z = blockIdx.z;
  if (z < 2) {
    int idx = blockIdx.x * 256 + threadIdx.x;   // B*N*128
    int j = idx & 127;
    int row = idx >> 7;
    int b = row / N_, n = row % N_;
    const float4* ir = (const float4*)(lnb + z * S_ + (size_t)row * C_);
    const float4* wr = (const float4*)(qvw + (size_t)j * C_);
    float acc = qvb[j];
#pragma unroll
    for (int t = 0; t < 16; ++t) {
      float4 a = ir[t], wv = wr[t];
      acc += a.x * wv.x + a.y * wv.y + a.z * wv.z + a.w * wv.w;
    }
    int jj = j & 63;
    int h = jj >> 3, d = jj & 7;
    float* dst = ((j < C_) ? qb : vb) + z * 2 * S_;
    dst[((size_t)(b * NH_ + h) * N_ + n) * HD_ + d] = acc;
  } else {
    if (blockIdx.x >= 1152) return;
    int idx = blockIdx.x * 256 + threadIdx.x;   // B*N*64
    int j = idx & 63;
    int row = idx >> 6;
    int b = row / N_, n = row % N_;
    const float4* ir = (const float4*)(zl + (size_t)row * C_);
    const float4* wr = (const float4*)(kw + (size_t)j * C_);
    float acc = kb[j];
#pragma unroll
    for (int t = 0; t < 16; ++t) {
      float4 a = ir[t], wv = wr[t];
      acc += a.x * wv.x + a.y * wv.y + a.z * wv.z + a.w * wv.w;
    }
    int h = j >> 3, d = j & 7;
    kk[((size_t)(b * NH_ + h) * N_ + n) * HD_ + d] = acc;
  }
}

// ---------------- attention v6: 2 queries/lane, 16 waves, no-max ----------
// grid (18, B*NH), block 1024. Wave strip = 144 keys; lane owns q0, q0+64.
#define AW 16
__global__ __launch_bounds__(1024, 8) void k_attn6(
    const float* __restrict__ xq, const float* __restrict__ xv,
    const float* __restrict__ yq, const float* __restrict__ yv,
    const float* __restrict__ kk,
    float* __restrict__ outx, float* __restrict__ outy) {
  __shared__ float pl[AW][2][64];
  __shared__ float pbuf[AW][8][64];
  int bh  = blockIdx.y;
  int qt  = blockIdx.x;
  int tid = threadIdx.x;
  int lane = tid & 63;
  int wave = __builtin_amdgcn_readfirstlane(tid >> 6);   // uniform -> scalar addrs
  int qA = qt * 128 + lane;
  int qB = qA + 64;
  size_t base = (size_t)bh * N_ * HD_;

  float4 qxA0 = ((const float4*)(xq + base + (size_t)qA * HD_))[0];
  float4 qxA1 = ((const float4*)(xq + base + (size_t)qA * HD_))[1];
  float4 qyA0 = ((const float4*)(yq + base + (size_t)qA * HD_))[0];
  float4 qyA1 = ((const float4*)(yq + base + (size_t)qA * HD_))[1];
  float4 qxB0 = ((const float4*)(xq + base + (size_t)qB * HD_))[0];
  float4 qxB1 = ((const float4*)(xq + base + (size_t)qB * HD_))[1];
  float4 qyB0 = ((const float4*)(yq + base + (size_t)qB * HD_))[0];
  float4 qyB1 = ((const float4*)(yq + base + (size_t)qB * HD_))[1];
  const float fs = S2_ * LOG2E_;
  qxA0.x *= fs; qxA0.y *= fs; qxA0.z *= fs; qxA0.w *= fs;
  qxA1.x *= fs; qxA1.y *= fs; qxA1.z *= fs; qxA1.w *= fs;
  qxB0.x *= fs; qxB0.y *= fs; qxB0.z *= fs; qxB0.w *= fs;
  qxB1.x *= fs; qxB1.y *= fs; qxB1.z *= fs; qxB1.w *= fs;

  float lA = 0.f, lB = 0.f;
  float axA[8] = {0,0,0,0,0,0,0,0}, ayA[8] = {0,0,0,0,0,0,0,0};
  float axB[8] = {0,0,0,0,0,0,0,0}, ayB[8] = {0,0,0,0,0,0,0,0};

  const float4* kp = (const float4*)(kk + base);
  const float4* xp = (const float4*)(xv + base);
  const float4* yp = (const float4*)(yv + base);
  int k0 = wave * (N_ / AW);
  for (int mi = k0; mi < k0 + N_ / AW; ++mi) {
    float4 ka  = kp[2 * mi];
    float4 kb2 = kp[2 * mi + 1];
    float s1A = qxA0.x*ka.x + qxA0.y*ka.y + qxA0.z*ka.z + qxA0.w*ka.w
              + qxA1.x*kb2.x + qxA1.y*kb2.y + qxA1.z*kb2.z + qxA1.w*kb2.w;
    float s2A = qyA0.x*ka.x + qyA0.y*ka.y + qyA0.z*ka.z + qyA0.w*ka.w
              + qyA1.x*kb2.x + qyA1.y*kb2.y + qyA1.z*kb2.z + qyA1.w*kb2.w;
    float s1B = qxB0.x*ka.x + qxB0.y*ka.y + qxB0.z*ka.z + qxB0.w*ka.w
              + qxB1.x*kb2.x + qxB1.y*kb2.y + qxB1.z*kb2.z + qxB1.w*kb2.w;
    float s2B = qyB0.x*ka.x + qyB0.y*ka.y + qyB0.z*ka.z + qyB0.w*ka.w
              + qyB1.x*kb2.x + qyB1.y*kb2.y + qyB1.z*kb2.z + qyB1.w*kb2.w;
    float pA = exp2f(s1A * s2A);
    float pB = exp2f(s1B * s2B);
    lA += pA; lB += pB;
    float4 xa = xp[2 * mi], xb = xp[2 * mi + 1];
    float4 ya = yp[2 * mi], yb = yp[2 * mi + 1];
    axA[0] += pA*xa.x; axA[1] += pA*xa.y; axA[2] += pA*xa.z; axA[3] += pA*xa.w;
    axA[4] += pA*xb.x; axA[5] += pA*xb.y; axA[6] += pA*xb.z; axA[7] += pA*xb.w;
    ayA[0] += pA*ya.x; ayA[1] += pA*ya.y; ayA[2] += pA*ya.z; ayA[3] += pA*ya.w;
    ayA[4] += pA*yb.x; ayA[5] += pA*yb.y; ayA[6] += pA*yb.z; ayA[7] += pA*yb.w;
    axB[0] += pB*xa.x; axB[1] += pB*xa.y; axB[2] += pB*xa.z; axB[3] += pB*xa.w;
    axB[4] += pB*xb.x; axB[5] += pB*xb.y; axB[6] += pB*xb.z; axB[7] += pB*xb.w;
    ayB[0] += pB*ya.x; ayB[1] += pB*ya.y; ayB[2] += pB*ya.z; ayB[3] += pB*ya.w;
    ayB[4] += pB*yb.x; ayB[5] += pB*yb.y; ayB[6] += pB*yb.z; ayB[7] += pB*yb.w;
  }
  pl[wave][0][lane] = lA;
  pl[wave][1][lane] = lB;
#pragma unroll
  for (int d = 0; d < 8; ++d) pbuf[wave][d][lane] = axA[d];
  __syncthreads();
  int b = bh / NH_, h = bh % NH_;
  float LinvA = 0.f, LinvB = 0.f;
  if (tid < 64) {
    float LA = 0.f, LB = 0.f;
#pragma unroll
    for (int w = 0; w < AW; ++w) { LA += pl[w][0][lane]; LB += pl[w][1][lane]; }
    LinvA = 1.f / LA; LinvB = 1.f / LB;
    float A[8] = {0,0,0,0,0,0,0,0};
#pragma unroll
    for (int w = 0; w < AW; ++w)
#pragma unroll
      for (int d = 0; d < 8; ++d) A[d] += pbuf[w][d][lane];
    float* o = outx + ((size_t)(b * N_ + qA)) * C_ + h * HD_;
#pragma unroll
    for (int d = 0; d < 8; ++d) o[d] = A[d] * LinvA;
  }
  __syncthreads();
#pragma unroll
  for (int d = 0; d < 8; ++d) pbuf[wave][d][lane] = ayA[d];
  __syncthreads();
  if (tid < 64) {
    float A[8] = {0,0,0,0,0,0,0,0};
#pragma unroll
    for (int w = 0; w < AW; ++w)
#pragma unroll
      for (int d = 0; d < 8; ++d) A[d] += pbuf[w][d][lane];
    float* o = outy + ((size_t)(b * N_ + qA)) * C_ + h * HD_;
#pragma unroll
    for (int d = 0; d < 8; ++d) o[d] = A[d] * LinvA;
  }
  __syncthreads();
#pragma unroll
  for (int d = 0; d < 8; ++d) pbuf[wave][d][lane] = axB[d];
  __syncthreads();
  if (tid < 64) {
    float A[8] = {0,0,0,0,0,0,0,0};
#pragma unroll
    for (int w = 0; w < AW; ++w)
#pragma unroll
      for (int d = 0; d < 8; ++d) A[d] += pbuf[w][d][lane];
    float* o = outx + ((size_t)(b * N_ + qB)) * C_ + h * HD_;
#pragma unroll
    for (int d = 0; d < 8; ++d) o[d] = A[d] * LinvB;
  }
  __syncthreads();
#pragma unroll
  for (int d = 0; d < 8; ++d) pbuf[wave][d][lane] = ayB[d];
  __syncthreads();
  if (tid < 64) {
    float A[8] = {0,0,0,0,0,0,0,0};
#pragma unroll
    for (int w = 0; w < AW; ++w)
#pragma unroll
      for (int d = 0; d < 8; ++d) A[d] += pbuf[w][d][lane];
    float* o = outy + ((size_t)(b * N_ + qB)) * C_ + h * HD_;
#pragma unroll
    for (int d = 0; d < 8; ++d) o[d] = A[d] * LinvB;
  }
}

// -------- proj + recomputed-BN residual, 2 px/thread, batched branches ----
// grid (18, C_, 2*B_), block 64
__global__ __launch_bounds__(64) void k_proj2(
    const float* __restrict__ attbase,
    const float* __restrict__ x, const float* __restrict__ y,
    const float* bg, const float* bb2, const float* bm, const float* bv,
    const float* __restrict__ pw, const float* __restrict__ pbias,
    float* __restrict__ outbase) {
  int p = blockIdx.x * 128 + threadIdx.x * 2;
  int c = blockIdx.y;
  int z = blockIdx.z;                 // branch*B_ + b
  int branch = z >> 1, b = z & 1;
  const float* att = attbase + branch * S_ + (size_t)b * N_ * C_;
  const float4* wr = (const float4*)(pw + (size_t)c * C_);
  float bias = pbias[c];
  float acc[2];
#pragma unroll
  for (int i = 0; i < 2; ++i) {
    const float4* ar = (const float4*)(att + (size_t)(p + i) * C_);
    float a = bias;
#pragma unroll
    for (int t = 0; t < 16; ++t) {
      float4 av = ar[t], wv = wr[t];
      a += av.x * wv.x + av.y * wv.y + av.z * wv.z + av.w * wv.w;
    }
    acc[i] = a;
  }
  float s  = bg[c] * rsqrtf(bv[c] + EPS_);
  float sh = bb2[c] - bm[c] * s;
  const float* xin = branch ? y : x;
  float2 r = *(const float2*)(xin + ((size_t)b * C_ + c) * N_ + p);
  size_t o = ((size_t)z * C_ + c) * N_ + p;
  *(float2*)(outbase + o) = make_float2(acc[0] + r.x * s + sh,
                                        acc[1] + r.y * s + sh);
}

// ------ conv1 of conv2_block: both branches + 2 couts + 2 px per thread ---
// grid (18, C_/2, B_), block 64
__global__ __launch_bounds__(64) void k_convp(
    const float* __restrict__ in, const float* __restrict__ w,
    const float* __restrict__ cb,
    const float* __restrict__ bg, const float* __restrict__ bbeta,
    const float* __restrict__ bm, const float* __restrict__ bv,
    float* __restrict__ out) {
  int p = blockIdx.x * 128 + threadIdx.x * 2;
  int c0 = blockIdx.y * 2;
  int b = blockIdx.z;
  int yy = p / W_, x0 = p % W_;
  const float* ix  = in + (size_t)b * C_ * N_;
  const float* iy2 = in + S_ + (size_t)b * C_ * N_;
  const float* w0r = w + (size_t)c0 * C_ * 9;
  const float* w1r = w0r + (size_t)C_ * 9;
  float bias0 = cb[c0], bias1 = cb[c0 + 1];
  float xa0 = bias0, xa1 = bias0, xb0 = bias1, xb1 = bias1;
  float ya0 = bias0, ya1 = bias0, yb0 = bias1, yb1 = bias1;
  for (int ci = 0; ci < C_; ++ci) {
    const float* ipx = ix + ci * N_;
    const float* ipy = iy2 + ci * N_;
    const float* wp0 = w0r + ci * 9;
    const float* wp1 = w1r + ci * 9;
#pragma unroll
    for (int ky = 0; ky < 3; ++ky) {
      int iyy = yy + ky - 1;
      if ((unsigned)iyy >= (unsigned)H_) continue;
      const float* rpx = ipx + iyy * W_;
      const float* rpy = ipy + iyy * W_;
      float2 mx = *(const float2*)(rpx + x0);
      float lx = (x0 > 0) ? rpx[x0 - 1] : 0.f;
      float rx = (x0 + 2 < W_) ? rpx[x0 + 2] : 0.f;
      float2 my = *(const float2*)(rpy + x0);
      float ly = (x0 > 0) ? rpy[x0 - 1] : 0.f;
      float ry = (x0 + 2 < W_) ? rpy[x0 + 2] : 0.f;
      float u0 = wp0[ky*3], u1 = wp0[ky*3+1], u2 = wp0[ky*3+2];
      float t0 = wp1[ky*3], t1 = wp1[ky*3+1], t2 = wp1[ky*3+2];
      xa0 += lx*u0 + mx.x*u1 + mx.y*u2;
      xa1 += mx.x*u0 + mx.y*u1 + rx*u2;
      xb0 += lx*t0 + mx.x*t1 + mx.y*t2;
      xb1 += mx.x*t0 + mx.y*t1 + rx*t2;
      ya0 += ly*u0 + my.x*u1 + my.y*u2;
      ya1 += my.x*u0 + my.y*u1 + ry*u2;
      yb0 += ly*t0 + my.x*t1 + my.y*t2;
      yb1 += my.x*t0 + my.y*t1 + ry*t2;
    }
  }
  float s0 = bg[c0] * rsqrtf(bv[c0] + EPS_);
  float sh0 = bbeta[c0] - bm[c0] * s0;
  float s1 = bg[c0+1] * rsqrtf(bv[c0+1] + EPS_);
  float sh1 = bbeta[c0+1] - bm[c0+1] * s1;
  size_t o = ((size_t)b * C_ + c0) * N_ + p;
  *(float2*)(out + o)           = make_float2(fmaxf(xa0*s0+sh0,0.f), fmaxf(xa1*s0+sh0,0.f));
  *(float2*)(out + o + N_)      = make_float2(fmaxf(xb0*s1+sh1,0.f), fmaxf(xb1*s1+sh1,0.f));
  *(float2*)(out + S_ + o)      = make_float2(fmaxf(ya0*s0+sh0,0.f), fmaxf(ya1*s0+sh0,0.f));
  *(float2*)(out + S_ + o + N_) = make_float2(fmaxf(yb0*s1+sh1,0.f), fmaxf(yb1*s1+sh1,0.f));
}

// ------ conv2 + bn + relu + residual + cat + bn2, fused epilogue ----------
// grid (18, C_/2, B_), block 64. fin image b at fin + b*finStride.
__global__ __launch_bounds__(64) void k_conv2cat(
    const float* __restrict__ in, const float* __restrict__ w,
    const float* __restrict__ cb,
    const float* __restrict__ bg, const float* __restrict__ bbeta,
    const float* __restrict__ bm, const float* __restrict__ bv,
    const float* __restrict__ resid,
    const float* __restrict__ g2, const float* __restrict__ b2,
    const float* __restrict__ m2, const float* __restrict__ v2,
    float* __restrict__ cat, float* __restrict__ fin, size_t finStride) {
  int p = blockIdx.x * 128 + threadIdx.x * 2;
  int c0 = blockIdx.y * 2;
  int b = blockIdx.z;
  int yy = p / W_, x0 = p % W_;
  const float* ix  = in + (size_t)b * C_ * N_;
  const float* iy2 = in + S_ + (size_t)b * C_ * N_;
  const float* w0r = w + (size_t)c0 * C_ * 9;
  const float* w1r = w0r + (size_t)C_ * 9;
  float bias0 = cb[c0], bias1 = cb[c0 + 1];
  float xa0 = bias0, xa1 = bias0, xb0 = bias1, xb1 = bias1;
  float ya0 = bias0, ya1 = bias0, yb0 = bias1, yb1 = bias1;
  for (int ci = 0; ci < C_; ++ci) {
    const float* ipx = ix + ci * N_;
    const float* ipy = iy2 + ci * N_;
    const float* wp0 = w0r + ci * 9;
    const float* wp1 = w1r + ci * 9;
#pragma unroll
    for (int ky = 0; ky < 3; ++ky) {
      int iyy = yy + ky - 1;
      if ((unsigned)iyy >= (unsigned)H_) continue;
      const float* rpx = ipx + iyy * W_;
      const float* rpy = ipy + iyy * W_;
      float2 mx = *(const float2*)(rpx + x0);
      float lx = (x0 > 0) ? rpx[x0 - 1] : 0.f;
      float rx = (x0 + 2 < W_) ? rpx[x0 + 2] : 0.f;
      float2 my = *(const float2*)(rpy + x0);
      float ly = (x0 > 0) ? rpy[x0 - 1] : 0.f;
      float ry = (x0 + 2 < W_) ? rpy[x0 + 2] : 0.f;
      float u0 = wp0[ky*3], u1 = wp0[ky*3+1], u2 = wp0[ky*3+2];
      float t0 = wp1[ky*3], t1 = wp1[ky*3+1], t2 = wp1[ky*3+2];
      xa0 += lx*u0 + mx.x*u1 + mx.y*u2;
      xa1 += mx.x*u0 + mx.y*u1 + rx*u2;
      xb0 += lx*t0 + mx.x*t1 + mx.y*t2;
      xb1 += mx.x*t0 + mx.y*t1 + rx*t2;
      ya0 += ly*u0 + my.x*u1 + my.y*u2;
      ya1 += my.x*u0 + my.y*u1 + ry*u2;
      yb0 += ly*t0 + my.x*t1 + my.y*t2;
      yb1 += my.x*t0 + my.y*t1 + ry*t2;
    }
  }
  float s0 = bg[c0] * rsqrtf(bv[c0] + EPS_);
  float sh0 = bbeta[c0] - bm[c0] * s0;
  float s1 = bg[c0+1] * rsqrtf(bv[c0+1] + EPS_);
  float sh1 = bbeta[c0+1] - bm[c0+1] * s1;
  float X0a = fmaxf(xa0*s0+sh0, 0.f), X0b = fmaxf(xa1*s0+sh0, 0.f);
  float X1a = fmaxf(xb0*s1+sh1, 0.f), X1b = fmaxf(xb1*s1+sh1, 0.f);
  float Y0a = fmaxf(ya0*s0+sh0, 0.f), Y0b = fmaxf(ya1*s0+sh0, 0.f);
  float Y1a = fmaxf(yb0*s1+sh1, 0.f), Y1b = fmaxf(yb1*s1+sh1, 0.f);
  size_t ro = ((size_t)b * C_ + c0) * N_ + p;
  float2 rX0 = *(const float2*)(resid + ro);
  float2 rX1 = *(const float2*)(resid + ro + N_);
  float2 rY0 = *(const float2*)(resid + S_ + ro);
  float2 rY1 = *(const float2*)(resid + S_ + ro + N_);
  X0a += rX0.x; X0b += rX0.y; X1a += rX1.x; X1b += rX1.y;
  Y0a += rY0.x; Y0b += rY0.y; Y1a += rY1.x; Y1b += rY1.y;
  float add0a = X0a + Y0a, add0b = X0b + Y0b;
  float add1a = X1a + Y1a, add1b = X1b + Y1b;
  float mul0a = X0a * Y0a, mul0b = X0b * Y0b;
  float mul1a = X1a * Y1a, mul1b = X1b * Y1b;
  size_t co = ((size_t)b * 2 * C_ + c0) * N_ + p;
  *(float2*)(cat + co)                     = make_float2(add0a, add0b);
  *(float2*)(cat + co + N_)                = make_float2(add1a, add1b);
  *(float2*)(cat + co + (size_t)C_ * N_)   = make_float2(mul0a, mul0b);
  *(float2*)(cat + co + (size_t)(C_+1)*N_) = make_float2(mul1a, mul1b);
  float fa0 = g2[c0]   * rsqrtf(v2[c0]   + EPS_), ga0 = b2[c0]   - m2[c0]   * fa0;
  float fa1 = g2[c0+1] * rsqrtf(v2[c0+1] + EPS_), ga1 = b2[c0+1] - m2[c0+1] * fa1;
  float fm0 = g2[C_+c0]   * rsqrtf(v2[C_+c0]   + EPS_), gm0 = b2[C_+c0]   - m2[C_+c0]   * fm0;
  float fm1 = g2[C_+c0+1] * rsqrtf(v2[C_+c0+1] + EPS_), gm1 = b2[C_+c0+1] - m2[C_+c0+1] * fm1;
  float* fb = fin + (size_t)b * finStride;
  size_t fo = (size_t)c0 * N_ + p;
  *(float2*)(fb + fo)                     = make_float2(add0a*fa0+ga0, add0b*fa0+ga0);
  *(float2*)(fb + fo + N_)                = make_float2(add1a*fa1+ga1, add1b*fa1+ga1);
  *(float2*)(fb + fo + (size_t)C_ * N_)   = make_float2(mul0a*fm0+gm0, mul0b*fm0+gm0);
  *(float2*)(fb + fo + (size_t)(C_+1)*N_) = make_float2(mul1a*fm1+gm1, mul1b*fm1+gm1);
}

// ------ f-branch 3x3 conv partial (64-cin half), 2 couts + 2 px -----------
// grid (18, C_, 2*B_), block 64. z: b = z&1, half = z>>1.
// partials: pout + (half*B_ + b... laid out (half*2 + b)*S_.
__global__ __launch_bounds__(64) void k_fconvs(
    const float* __restrict__ in, size_t inStride,
    const float* __restrict__ w,
    float* __restrict__ pout) {
  int p = blockIdx.x * 128 + threadIdx.x * 2;
  int c0 = blockIdx.y * 2;
  int z = blockIdx.z;
  int b = z & 1, half = z >> 1;
  int yy = p / W_, x0 = p % W_;
  const float* ib = in + (size_t)b * inStride;
  const float* w0r = w + (size_t)c0 * (2 * C_) * 9;
  const float* w1r = w0r + (size_t)(2 * C_) * 9;
  float a00 = 0.f, a01 = 0.f, a10 = 0.f, a11 = 0.f;
  int ci0 = half * C_;
  for (int ci = ci0; ci < ci0 + C_; ++ci) {
    const float* ip = ib + ci * N_;
    const float* wp0 = w0r + ci * 9;
    const float* wp1 = w1r + ci * 9;
#pragma unroll
    for (int ky = 0; ky < 3; ++ky) {
      int iyy = yy + ky - 1;
      if ((unsigned)iyy >= (unsigned)H_) continue;
      const float* rp = ip + iyy * W_;
      float2 mid = *(const float2*)(rp + x0);
      float vL = (x0 > 0) ? rp[x0 - 1] : 0.f;
      float vR = (x0 + 2 < W_) ? rp[x0 + 2] : 0.f;
      float u0 = wp0[ky*3], u1 = wp0[ky*3+1], u2 = wp0[ky*3+2];
      float t0 = wp1[ky*3], t1 = wp1[ky*3+1], t2 = wp1[ky*3+2];
      a00 += vL*u0 + mid.x*u1 + mid.y*u2;
      a01 += mid.x*u0 + mid.y*u1 + vR*u2;
      a10 += vL*t0 + mid.x*t1 + mid.y*t2;
      a11 += mid.x*t0 + mid.y*t1 + vR*t2;
    }
  }
  size_t o = (size_t)(half * 2 + b) * S_ + (size_t)c0 * N_ + p;
  *(float2*)(pout + o)      = make_float2(a00, a01);
  *(float2*)(pout + o + N_) = make_float2(a10, a11);
}

// ------ combine halves + bn + relu, float4 --------------------------------
// grid 576, block 256. p0 at pbase + b*S_, p1 at pbase + (2+b)*S_.
__global__ void k_comb(const float* __restrict__ pbase,
                       const float* __restrict__ g, const float* __restrict__ b2,
                       const float* __restrict__ m, const float* __restrict__ v,
                       float* __restrict__ out, size_t outStride) {
  int t = blockIdx.x * 256 + threadIdx.x;
  int p4 = t * 4;
  int n = p4 % N_;
  int c = (p4 / N_) % (2 * C_);
  int b = p4 / (2 * C_ * N_);
  size_t off = (size_t)b * S_ + (size_t)c * N_ + n;
  float4 a = *(const float4*)(pbase + off);
  float4 d = *(const float4*)(pbase + 2 * S_ + off);
  float s  = g[c] * rsqrtf(v[c] + EPS_);
  float sh = b2[c] - m[c] * s;
  float4 r;
  r.x = fmaxf((a.x + d.x) * s + sh, 0.f);
  r.y = fmaxf((a.y + d.y) * s + sh, 0.f);
  r.z = fmaxf((a.z + d.z) * s + sh, 0.f);
  r.w = fmaxf((a.w + d.w) * s + sh, 0.f);
  *(float4*)(out + (size_t)b * outStride + (size_t)c * N_ + n) = r;
}

// -------- final 1x1 conv + bias + cat add, 2 px/thread --------------------
// grid (18, 2C, B), block 64. f2 image b at f2 + b*fStride.
__global__ __launch_bounds__(64) void k_final2(
    const float* __restrict__ f2, size_t fStride,
    const float* __restrict__ cat,
    const float* __restrict__ w, const float* __restrict__ fb,
    float* __restrict__ out) {
  int p = blockIdx.x * 128 + threadIdx.x * 2;
  int c = blockIdx.y, b = blockIdx.z;
  const float* fr = f2 + (size_t)b * fStride;
  const float* wr = w + (size_t)c * 2 * C_;
  float a0 = fb[c], a1 = a0;
  for (int j = 0; j < 2 * C_; ++j) {
    float2 fv = *(const float2*)(fr + (size_t)j * N_ + p);
    float wv = wr[j];
    a0 += wv * fv.x; a1 += wv * fv.y;
  }
  size_t o = ((size_t)b * 2 * C_ + c) * N_ + p;
  float2 cv = *(const float2*)(cat + o);
  *(float2*)(out + o) = make_float2(a0 + cv.x, a1 + cv.y);
}

extern "C" void kernel_launch(void* const* d_in, const int* in_sizes, int n_in,
                              void* d_out, int out_size, void* d_ws, size_t ws_size,
                              hipStream_t stream) {
  const float* x       = (const float*)d_in[0];
  const float* y       = (const float*)d_in[1];
  const float* pconv_w = (const float*)d_in[2];
  const float* pconv_b = (const float*)d_in[3];
  const float* bnd_g = (const float*)d_in[4];
  const float* bnd_b = (const float*)d_in[5];
  const float* bnd_m = (const float*)d_in[6];
  const float* bnd_v = (const float*)d_in[7];
  const float* lnx_g = (const float*)d_in[8];
  const float* lnx_b = (const float*)d_in[9];
  const float* lny_g = (const float*)d_in[10];
  const float* lny_b = (const float*)d_in[11];
  const float* lnz_g = (const float*)d_in[12];
  const float* lnz_b = (const float*)d_in[13];
  const float* k_w   = (const float*)d_in[14];
  const float* k_b   = (const float*)d_in[15];
  const float* qv_w  = (const float*)d_in[16];
  const float* qv_b  = (const float*)d_in[17];
  const float* proj_w = (const float*)d_in[18];
  const float* proj_b = (const float*)d_in[19];
  const float* c2w1  = (const float*)d_in[20];
  const float* c2b1  = (const float*)d_in[21];
  const float* c2bn1_g = (const float*)d_in[22];
  const float* c2bn1_b = (const float*)d_in[23];
  const float* c2bn1_m = (const float*)d_in[24];
  const float* c2bn1_v = (const float*)d_in[25];
  const float* c2w2  = (const float*)d_in[26];
  const float* c2b2  = (const float*)d_in[27];
  const float* c2bn2_g = (const float*)d_in[28];
  const float* c2bn2_b = (const float*)d_in[29];
  const float* c2bn2_m = (const float*)d_in[30];
  const float* c2bn2_v = (const float*)d_in[31];
  const float* bn2_g = (const float*)d_in[32];
  const float* bn2_b = (const float*)d_in[33];
  const float* bn2_m = (const float*)d_in[34];
  const float* bn2_v = (const float*)d_in[35];
  const float* f1w   = (const float*)d_in[36];
  const float* fbn1_g = (const float*)d_in[37];
  const float* fbn1_b = (const float*)d_in[38];
  const float* fbn1_m = (const float*)d_in[39];
  const float* fbn1_v = (const float*)d_in[40];
  const float* f2w   = (const float*)d_in[41];
  const float* fbn2_g = (const float*)d_in[42];
  const float* fbn2_b = (const float*)d_in[43];
  const float* fbn2_m = (const float*)d_in[44];
  const float* fbn2_v = (const float*)d_in[45];
  const float* f3w   = (const float*)d_in[46];
  const float* f3b   = (const float*)d_in[47];

  // 8-slot workspace plan:
  //   A: k_pre -> xl(1) yl(2) zl(3)
  //   B: qvk -> xq(4) xv(5) yq(6) yv(7); kk(0)
  //   C: attn6 -> att_xo(1) att_yo(2)
  //   D: proj -> xo(3,4)
  //   E: convp -> tmp(5,6)
  //   F: conv2cat -> cat(1,2), fin -> 0 and 7 (stride 7S)
  //   G1: fconvs f1 partials -> 3,4,5,6 ; G2: comb -> 0,7
  //   G3: fconvs f2 partials -> 3,4,5,6 ; G4: comb -> 0,7
  //   H: final reads (0,7) + cat(1,2)
  float* ws = (float*)d_ws;
  float* sl0 = ws + 0 * S_;
  float* sl1 = ws + 1 * S_;
  float* sl2 = ws + 2 * S_;
  float* sl3 = ws + 3 * S_;
  float* sl4 = ws + 4 * S_;
  float* sl5 = ws + 5 * S_;

  // A. fused pconv + bn + ln
  k_pre<<<B_ * N_, 64, 0, stream>>>(x, y, pconv_w, pconv_b,
                                    bnd_g, bnd_b, bnd_m, bnd_v,
                                    lnx_g, lnx_b, lny_g, lny_b, lnz_g, lnz_b,
                                    sl1, sl2, sl3);
  // B. fused qv + kproj
  {
    dim3 g(2304, 1, 3);
    k_qvk<<<g, 256, 0, stream>>>(sl1, sl3, qv_w, qv_b, k_w, k_b, sl4, sl5, sl0);
  }
  // C. attention v6 -> att_xo(1), att_yo(2)
  {
    dim3 g(N_ / 128, B_ * NH_);
    k_attn6<<<g, 1024, 0, stream>>>(sl4, sl5, ws + 6 * S_, ws + 7 * S_, sl0,
                                    sl1, sl2);
  }
  // D. proj batched -> xo(3,4)
  {
    dim3 g(18, C_, 2 * B_);
    k_proj2<<<g, 64, 0, stream>>>(sl1, x, y, bnd_g, bnd_b, bnd_m, bnd_v,
                                  proj_w, proj_b, sl3);
  }
  // E. conv1 (both branches, 2 couts) -> tmp(5,6)
  {
    dim3 g(18, C_ / 2, B_);
    k_convp<<<g, 64, 0, stream>>>(sl3, c2w1, c2b1,
        c2bn1_g, c2bn1_b, c2bn1_m, c2bn1_v, sl5);
  }
  // F. conv2 + resid + cat + bn2 -> cat(1,2), fin(0 / 7)
  {
    dim3 g(18, C_ / 2, B_);
    k_conv2cat<<<g, 64, 0, stream>>>(sl5, c2w2, c2b2,
        c2bn2_g, c2bn2_b, c2bn2_m, c2bn2_v, sl3,
        bn2_g, bn2_b, bn2_m, bn2_v, sl1, sl0, 7 * S_);
  }
  // G. f-branch convs, ci-split + combine
  {
    dim3 g(18, C_, 2 * B_);
    k_fconvs<<<g, 64, 0, stream>>>(sl0, 7 * S_, f1w, sl3);
    k_comb<<<576, 256, 0, stream>>>(sl3, fbn1_g, fbn1_b, fbn1_m, fbn1_v,
                                    sl0, 7 * S_);
    k_fconvs<<<g, 64, 0, stream>>>(sl0, 7 * S_, f2w, sl3);
    k_comb<<<576, 256, 0, stream>>>(sl3, fbn2_g, fbn2_b, fbn2_m, fbn2_v,
                                    sl0, 7 * S_);
  }
  // H. final 1x1 + cat add -> fp32 out
  {
    dim3 g(18, 2 * C_, B_);
    k_final2<<<g, 64, 0, stream>>>(sl0, 7 * S_, sl1, f3w, f3b, (float*)d_out);
  }
}

// Round 10
// 723.070 us; speedup vs baseline: 1.1889x; 1.1889x over previous
//
#include <hip/hip_runtime.h>
#include <hip/hip_bf16.h>

#define B_   2
#define C_   64
#define H_   48
#define W_   48
#define N_   (H_*W_)     // 2304
#define NH_  8
#define HD_  8
#define EPS_ 1e-5f
#define S2_  0.125f      // scale^2 = 1/hd
#define LOG2E_ 1.44269504f
#define S_   ((size_t)B_ * C_ * N_)   // 294912 floats per workspace slot

__device__ __forceinline__ float wsum64(float v) {
#pragma unroll
  for (int o = 32; o > 0; o >>= 1) v += __shfl_xor(v, o, 64);
  return v;
}

__device__ __forceinline__ float ln_val(float t, float g, float b) {
  float mu  = wsum64(t) * (1.0f / 64.0f);
  float d   = t - mu;
  float var = wsum64(d * d) * (1.0f / 64.0f);
  return d * rsqrtf(var + EPS_) * g + b;
}

// ---- fused 1x1 pconv + BN + 3x LayerNorm; block = one (b,n) row ----------
// grid B*N, block 64 (lane = channel)
__global__ __launch_bounds__(64) void k_pre(
    const float* __restrict__ x, const float* __restrict__ y,
    const float* __restrict__ pw, const float* __restrict__ pb,
    const float* g, const float* bb, const float* m, const float* v,
    const float* lnxg, const float* lnxb,
    const float* lnyg, const float* lnyb,
    const float* lnzg, const float* lnzb,
    float* __restrict__ xl, float* __restrict__ yl, float* __restrict__ zl) {
  __shared__ float xs[64], ys[64];
  int row = blockIdx.x;            // b*N + n
  int c = threadIdx.x;
  int b = row / N_, n = row % N_;
  float xv = x[(size_t)(b * C_ + c) * N_ + n];
  float yv = y[(size_t)(b * C_ + c) * N_ + n];
  xs[c] = xv; ys[c] = yv;
  __syncthreads();
  const float4* wr  = (const float4*)(pw + (size_t)c * 2 * C_);
  const float4* xs4 = (const float4*)xs;
  const float4* ys4 = (const float4*)ys;
  float acc = pb[c];
#pragma unroll
  for (int t = 0; t < 16; ++t) {
    float4 a = xs4[t], wv = wr[t];
    acc += a.x * wv.x + a.y * wv.y + a.z * wv.z + a.w * wv.w;
  }
#pragma unroll
  for (int t = 0; t < 16; ++t) {
    float4 a = ys4[t], wv = wr[16 + t];
    acc += a.x * wv.x + a.y * wv.y + a.z * wv.z + a.w * wv.w;
  }
  float s  = g[c] * rsqrtf(v[c] + EPS_);
  float sh = bb[c] - m[c] * s;
  float tx = xv * s + sh;
  xl[(size_t)row * C_ + c] = ln_val(tx, lnxg[c], lnxb[c]);
  float ty = yv * s + sh;
  yl[(size_t)row * C_ + c] = ln_val(ty, lnyg[c], lnyb[c]);
  float tz = acc * s + sh;
  zl[(size_t)row * C_ + c] = ln_val(tz, lnzg[c], lnzb[c]);
}

// ------------- fused qv (both branches) + k projection --------------------
// grid (2304, 1, 3), block 256. z=0,1: qv branch z; z=2: kproj (first 1152 blocks)
__global__ void k_qvk(const float* __restrict__ lnb, const float* __restrict__ zl,
                      const float* __restrict__ qvw, const float* __restrict__ qvb,
                      const float* __restrict__ kw, const float* __restrict__ kb,
                      float* __restrict__ qb, float* __restrict__ vb,
                      float* __restrict__ kk) {
  int z = blockIdx.z;
  if (z < 2) {
    int idx = blockIdx.x * 256 + threadIdx.x;   // B*N*128
    int j = idx & 127;
    int row = idx >> 7;
    int b = row / N_, n = row % N_;
    const float4* ir = (const float4*)(lnb + z * S_ + (size_t)row * C_);
    const float4* wr = (const float4*)(qvw + (size_t)j * C_);
    float acc = qvb[j];
#pragma unroll
    for (int t = 0; t < 16; ++t) {
      float4 a = ir[t], wv = wr[t];
      acc += a.x * wv.x + a.y * wv.y + a.z * wv.z + a.w * wv.w;
    }
    int jj = j & 63;
    int h = jj >> 3, d = jj & 7;
    float* dst = ((j < C_) ? qb : vb) + z * 2 * S_;
    dst[((size_t)(b * NH_ + h) * N_ + n) * HD_ + d] = acc;
  } else {
    if (blockIdx.x >= 1152) return;
    int idx = blockIdx.x * 256 + threadIdx.x;   // B*N*64
    int j = idx & 63;
    int row = idx >> 6;
    int b = row / N_, n = row % N_;
    const float4* ir = (const float4*)(zl + (size_t)row * C_);
    const float4* wr = (const float4*)(kw + (size_t)j * C_);
    float acc = kb[j];
#pragma unroll
    for (int t = 0; t < 16; ++t) {
      float4 a = ir[t], wv = wr[t];
      acc += a.x * wv.x + a.y * wv.y + a.z * wv.z + a.w * wv.w;
    }
    int h = j >> 3, d = j & 7;
    kk[((size_t)(b * NH_ + h) * N_ + n) * HD_ + d] = acc;
  }
}

// ---------------- attention v6b: 2 queries/lane, 16 waves, no-max ---------
// grid (18, B*NH), block 1024, launch_bounds(1024,4) -> 128 VGPR (no spill).
#define AW 16
__global__ __launch_bounds__(1024, 4) void k_attn6(
    const float* __restrict__ xq, const float* __restrict__ xv,
    const float* __restrict__ yq, const float* __restrict__ yv,
    const float* __restrict__ kk,
    float* __restrict__ outx, float* __restrict__ outy) {
  __shared__ float pl[AW][2][64];
  __shared__ float pbuf[AW][8][64];
  int bh  = blockIdx.y;
  int qt  = blockIdx.x;
  int tid = threadIdx.x;
  int lane = tid & 63;
  int wave = __builtin_amdgcn_readfirstlane(tid >> 6);   // uniform -> scalar addrs
  int qA = qt * 128 + lane;
  int qB = qA + 64;
  size_t base = (size_t)bh * N_ * HD_;

  float4 qxA0 = ((const float4*)(xq + base + (size_t)qA * HD_))[0];
  float4 qxA1 = ((const float4*)(xq + base + (size_t)qA * HD_))[1];
  float4 qyA0 = ((const float4*)(yq + base + (size_t)qA * HD_))[0];
  float4 qyA1 = ((const float4*)(yq + base + (size_t)qA * HD_))[1];
  float4 qxB0 = ((const float4*)(xq + base + (size_t)qB * HD_))[0];
  float4 qxB1 = ((const float4*)(xq + base + (size_t)qB * HD_))[1];
  float4 qyB0 = ((const float4*)(yq + base + (size_t)qB * HD_))[0];
  float4 qyB1 = ((const float4*)(yq + base + (size_t)qB * HD_))[1];
  const float fs = S2_ * LOG2E_;
  qxA0.x *= fs; qxA0.y *= fs; qxA0.z *= fs; qxA0.w *= fs;
  qxA1.x *= fs; qxA1.y *= fs; qxA1.z *= fs; qxA1.w *= fs;
  qxB0.x *= fs; qxB0.y *= fs; qxB0.z *= fs; qxB0.w *= fs;
  qxB1.x *= fs; qxB1.y *= fs; qxB1.z *= fs; qxB1.w *= fs;

  float lA = 0.f, lB = 0.f;
  float axA[8] = {0,0,0,0,0,0,0,0}, ayA[8] = {0,0,0,0,0,0,0,0};
  float axB[8] = {0,0,0,0,0,0,0,0}, ayB[8] = {0,0,0,0,0,0,0,0};

  const float4* kp = (const float4*)(kk + base);
  const float4* xp = (const float4*)(xv + base);
  const float4* yp = (const float4*)(yv + base);
  int k0 = wave * (N_ / AW);
  for (int mi = k0; mi < k0 + N_ / AW; ++mi) {
    float4 ka  = kp[2 * mi];
    float4 kb2 = kp[2 * mi + 1];
    float s1A = qxA0.x*ka.x + qxA0.y*ka.y + qxA0.z*ka.z + qxA0.w*ka.w
              + qxA1.x*kb2.x + qxA1.y*kb2.y + qxA1.z*kb2.z + qxA1.w*kb2.w;
    float s2A = qyA0.x*ka.x + qyA0.y*ka.y + qyA0.z*ka.z + qyA0.w*ka.w
              + qyA1.x*kb2.x + qyA1.y*kb2.y + qyA1.z*kb2.z + qyA1.w*kb2.w;
    float s1B = qxB0.x*ka.x + qxB0.y*ka.y + qxB0.z*ka.z + qxB0.w*ka.w
              + qxB1.x*kb2.x + qxB1.y*kb2.y + qxB1.z*kb2.z + qxB1.w*kb2.w;
    float s2B = qyB0.x*ka.x + qyB0.y*ka.y + qyB0.z*ka.z + qyB0.w*ka.w
              + qyB1.x*kb2.x + qyB1.y*kb2.y + qyB1.z*kb2.z + qyB1.w*kb2.w;
    float pA = exp2f(s1A * s2A);
    float pB = exp2f(s1B * s2B);
    lA += pA; lB += pB;
    float4 xa = xp[2 * mi], xb = xp[2 * mi + 1];
    float4 ya = yp[2 * mi], yb = yp[2 * mi + 1];
    axA[0] += pA*xa.x; axA[1] += pA*xa.y; axA[2] += pA*xa.z; axA[3] += pA*xa.w;
    axA[4] += pA*xb.x; axA[5] += pA*xb.y; axA[6] += pA*xb.z; axA[7] += pA*xb.w;
    ayA[0] += pA*ya.x; ayA[1] += pA*ya.y; ayA[2] += pA*ya.z; ayA[3] += pA*ya.w;
    ayA[4] += pA*yb.x; ayA[5] += pA*yb.y; ayA[6] += pA*yb.z; ayA[7] += pA*yb.w;
    axB[0] += pB*xa.x; axB[1] += pB*xa.y; axB[2] += pB*xa.z; axB[3] += pB*xa.w;
    axB[4] += pB*xb.x; axB[5] += pB*xb.y; axB[6] += pB*xb.z; axB[7] += pB*xb.w;
    ayB[0] += pB*ya.x; ayB[1] += pB*ya.y; ayB[2] += pB*ya.z; ayB[3] += pB*ya.w;
    ayB[4] += pB*yb.x; ayB[5] += pB*yb.y; ayB[6] += pB*yb.z; ayB[7] += pB*yb.w;
  }
  pl[wave][0][lane] = lA;
  pl[wave][1][lane] = lB;
#pragma unroll
  for (int d = 0; d < 8; ++d) pbuf[wave][d][lane] = axA[d];
  __syncthreads();
  int b = bh / NH_, h = bh % NH_;
  float LinvA = 0.f, LinvB = 0.f;
  if (tid < 64) {
    float LA = 0.f, LB = 0.f;
#pragma unroll
    for (int w = 0; w < AW; ++w) { LA += pl[w][0][lane]; LB += pl[w][1][lane]; }
    LinvA = 1.f / LA; LinvB = 1.f / LB;
    float A[8] = {0,0,0,0,0,0,0,0};
#pragma unroll
    for (int w = 0; w < AW; ++w)
#pragma unroll
      for (int d = 0; d < 8; ++d) A[d] += pbuf[w][d][lane];
    float* o = outx + ((size_t)(b * N_ + qA)) * C_ + h * HD_;
#pragma unroll
    for (int d = 0; d < 8; ++d) o[d] = A[d] * LinvA;
  }
  __syncthreads();
#pragma unroll
  for (int d = 0; d < 8; ++d) pbuf[wave][d][lane] = ayA[d];
  __syncthreads();
  if (tid < 64) {
    float A[8] = {0,0,0,0,0,0,0,0};
#pragma unroll
    for (int w = 0; w < AW; ++w)
#pragma unroll
      for (int d = 0; d < 8; ++d) A[d] += pbuf[w][d][lane];
    float* o = outy + ((size_t)(b * N_ + qA)) * C_ + h * HD_;
#pragma unroll
    for (int d = 0; d < 8; ++d) o[d] = A[d] * LinvA;
  }
  __syncthreads();
#pragma unroll
  for (int d = 0; d < 8; ++d) pbuf[wave][d][lane] = axB[d];
  __syncthreads();
  if (tid < 64) {
    float A[8] = {0,0,0,0,0,0,0,0};
#pragma unroll
    for (int w = 0; w < AW; ++w)
#pragma unroll
      for (int d = 0; d < 8; ++d) A[d] += pbuf[w][d][lane];
    float* o = outx + ((size_t)(b * N_ + qB)) * C_ + h * HD_;
#pragma unroll
    for (int d = 0; d < 8; ++d) o[d] = A[d] * LinvB;
  }
  __syncthreads();
#pragma unroll
  for (int d = 0; d < 8; ++d) pbuf[wave][d][lane] = ayB[d];
  __syncthreads();
  if (tid < 64) {
    float A[8] = {0,0,0,0,0,0,0,0};
#pragma unroll
    for (int w = 0; w < AW; ++w)
#pragma unroll
      for (int d = 0; d < 8; ++d) A[d] += pbuf[w][d][lane];
    float* o = outy + ((size_t)(b * N_ + qB)) * C_ + h * HD_;
#pragma unroll
    for (int d = 0; d < 8; ++d) o[d] = A[d] * LinvB;
  }
}

// -------- proj + recomputed-BN residual, 2 px/thread, batched branches ----
// grid (18, C_, 2*B_), block 64. out layout z*C*N, z = branch*B_ + b.
__global__ __launch_bounds__(64) void k_proj2(
    const float* __restrict__ attbase,
    const float* __restrict__ x, const float* __restrict__ y,
    const float* bg, const float* bb2, const float* bm, const float* bv,
    const float* __restrict__ pw, const float* __restrict__ pbias,
    float* __restrict__ outbase) {
  int p = blockIdx.x * 128 + threadIdx.x * 2;
  int c = blockIdx.y;
  int z = blockIdx.z;                 // branch*B_ + b
  int branch = z >> 1, b = z & 1;
  const float* att = attbase + branch * S_ + (size_t)b * N_ * C_;
  const float4* wr = (const float4*)(pw + (size_t)c * C_);
  float bias = pbias[c];
  float acc[2];
#pragma unroll
  for (int i = 0; i < 2; ++i) {
    const float4* ar = (const float4*)(att + (size_t)(p + i) * C_);
    float a = bias;
#pragma unroll
    for (int t = 0; t < 16; ++t) {
      float4 av = ar[t], wv = wr[t];
      a += av.x * wv.x + av.y * wv.y + av.z * wv.z + av.w * wv.w;
    }
    acc[i] = a;
  }
  float s  = bg[c] * rsqrtf(bv[c] + EPS_);
  float sh = bb2[c] - bm[c] * s;
  const float* xin = branch ? y : x;
  float2 r = *(const float2*)(xin + ((size_t)b * C_ + c) * N_ + p);
  size_t o = ((size_t)z * C_ + c) * N_ + p;
  *(float2*)(outbase + o) = make_float2(acc[0] + r.x * s + sh,
                                        acc[1] + r.y * s + sh);
}

// ------ conv1 of conv2_block: one branch per z, 2 couts + 2 px ------------
// grid (18, C_/2, 2*B_), block 64. z = branch*B_ + b (layout z*C*N).
__global__ __launch_bounds__(64) void k_convp(
    const float* __restrict__ in, const float* __restrict__ w,
    const float* __restrict__ cb,
    const float* __restrict__ bg, const float* __restrict__ bbeta,
    const float* __restrict__ bm, const float* __restrict__ bv,
    float* __restrict__ out) {
  int p = blockIdx.x * 128 + threadIdx.x * 2;
  int c0 = blockIdx.y * 2;
  int z = blockIdx.z;
  int yy = p / W_, x0 = p % W_;
  const float* ib = in + (size_t)z * C_ * N_;
  const float* w0r = w + (size_t)c0 * C_ * 9;
  const float* w1r = w0r + (size_t)C_ * 9;
  float bias0 = cb[c0], bias1 = cb[c0 + 1];
  float a00 = bias0, a01 = bias0, a10 = bias1, a11 = bias1;
  for (int ci = 0; ci < C_; ++ci) {
    const float* ip = ib + ci * N_;
    const float* wp0 = w0r + ci * 9;
    const float* wp1 = w1r + ci * 9;
#pragma unroll
    for (int ky = 0; ky < 3; ++ky) {
      int iyy = yy + ky - 1;
      if ((unsigned)iyy >= (unsigned)H_) continue;
      const float* rp = ip + iyy * W_;
      float2 mid = *(const float2*)(rp + x0);
      float vL = (x0 > 0) ? rp[x0 - 1] : 0.f;
      float vR = (x0 + 2 < W_) ? rp[x0 + 2] : 0.f;
      float u0 = wp0[ky*3], u1 = wp0[ky*3+1], u2 = wp0[ky*3+2];
      float t0 = wp1[ky*3], t1 = wp1[ky*3+1], t2 = wp1[ky*3+2];
      a00 += vL*u0 + mid.x*u1 + mid.y*u2;
      a01 += mid.x*u0 + mid.y*u1 + vR*u2;
      a10 += vL*t0 + mid.x*t1 + mid.y*t2;
      a11 += mid.x*t0 + mid.y*t1 + vR*t2;
    }
  }
  float s0 = bg[c0] * rsqrtf(bv[c0] + EPS_);
  float sh0 = bbeta[c0] - bm[c0] * s0;
  float s1 = bg[c0+1] * rsqrtf(bv[c0+1] + EPS_);
  float sh1 = bbeta[c0+1] - bm[c0+1] * s1;
  size_t o = (size_t)z * C_ * N_ + (size_t)c0 * N_ + p;
  *(float2*)(out + o)      = make_float2(fmaxf(a00*s0+sh0,0.f), fmaxf(a01*s0+sh0,0.f));
  *(float2*)(out + o + N_) = make_float2(fmaxf(a10*s1+sh1,0.f), fmaxf(a11*s1+sh1,0.f));
}

// ------ conv2 + bn + relu + residual + cat + bn2, fused epilogue ----------
// grid (18, C_/2, B_), block 64. in/resid layout [branch][b][C][N], branch
// stride S_. fin image b at fin + b*finStride.
__global__ __launch_bounds__(64) void k_conv2cat(
    const float* __restrict__ in, const float* __restrict__ w,
    const float* __restrict__ cb,
    const float* __restrict__ bg, const float* __restrict__ bbeta,
    const float* __restrict__ bm, const float* __restrict__ bv,
    const float* __restrict__ resid,
    const float* __restrict__ g2, const float* __restrict__ b2,
    const float* __restrict__ m2, const float* __restrict__ v2,
    float* __restrict__ cat, float* __restrict__ fin, size_t finStride) {
  int p = blockIdx.x * 128 + threadIdx.x * 2;
  int c0 = blockIdx.y * 2;
  int b = blockIdx.z;
  int yy = p / W_, x0 = p % W_;
  const float* ix  = in + (size_t)b * C_ * N_;
  const float* iy2 = in + S_ + (size_t)b * C_ * N_;
  const float* w0r = w + (size_t)c0 * C_ * 9;
  const float* w1r = w0r + (size_t)C_ * 9;
  float bias0 = cb[c0], bias1 = cb[c0 + 1];
  float xa0 = bias0, xa1 = bias0, xb0 = bias1, xb1 = bias1;
  float ya0 = bias0, ya1 = bias0, yb0 = bias1, yb1 = bias1;
  for (int ci = 0; ci < C_; ++ci) {
    const float* ipx = ix + ci * N_;
    const float* ipy = iy2 + ci * N_;
    const float* wp0 = w0r + ci * 9;
    const float* wp1 = w1r + ci * 9;
#pragma unroll
    for (int ky = 0; ky < 3; ++ky) {
      int iyy = yy + ky - 1;
      if ((unsigned)iyy >= (unsigned)H_) continue;
      const float* rpx = ipx + iyy * W_;
      const float* rpy = ipy + iyy * W_;
      float2 mx = *(const float2*)(rpx + x0);
      float lx = (x0 > 0) ? rpx[x0 - 1] : 0.f;
      float rx = (x0 + 2 < W_) ? rpx[x0 + 2] : 0.f;
      float2 my = *(const float2*)(rpy + x0);
      float ly = (x0 > 0) ? rpy[x0 - 1] : 0.f;
      float ry = (x0 + 2 < W_) ? rpy[x0 + 2] : 0.f;
      float u0 = wp0[ky*3], u1 = wp0[ky*3+1], u2 = wp0[ky*3+2];
      float t0 = wp1[ky*3], t1 = wp1[ky*3+1], t2 = wp1[ky*3+2];
      xa0 += lx*u0 + mx.x*u1 + mx.y*u2;
      xa1 += mx.x*u0 + mx.y*u1 + rx*u2;
      xb0 += lx*t0 + mx.x*t1 + mx.y*t2;
      xb1 += mx.x*t0 + mx.y*t1 + rx*t2;
      ya0 += ly*u0 + my.x*u1 + my.y*u2;
      ya1 += my.x*u0 + my.y*u1 + ry*u2;
      yb0 += ly*t0 + my.x*t1 + my.y*t2;
      yb1 += my.x*t0 + my.y*t1 + ry*t2;
    }
  }
  float s0 = bg[c0] * rsqrtf(bv[c0] + EPS_);
  float sh0 = bbeta[c0] - bm[c0] * s0;
  float s1 = bg[c0+1] * rsqrtf(bv[c0+1] + EPS_);
  float sh1 = bbeta[c0+1] - bm[c0+1] * s1;
  float X0a = fmaxf(xa0*s0+sh0, 0.f), X0b = fmaxf(xa1*s0+sh0, 0.f);
  float X1a = fmaxf(xb0*s1+sh1, 0.f), X1b = fmaxf(xb1*s1+sh1, 0.f);
  float Y0a = fmaxf(ya0*s0+sh0, 0.f), Y0b = fmaxf(ya1*s0+sh0, 0.f);
  float Y1a = fmaxf(yb0*s1+sh1, 0.f), Y1b = fmaxf(yb1*s1+sh1, 0.f);
  size_t ro = ((size_t)b * C_ + c0) * N_ + p;
  float2 rX0 = *(const float2*)(resid + ro);
  float2 rX1 = *(const float2*)(resid + ro + N_);
  float2 rY0 = *(const float2*)(resid + S_ + ro);        // branch stride = S_
  float2 rY1 = *(const float2*)(resid + S_ + ro + N_);
  X0a += rX0.x; X0b += rX0.y; X1a += rX1.x; X1b += rX1.y;
  Y0a += rY0.x; Y0b += rY0.y; Y1a += rY1.x; Y1b += rY1.y;
  float add0a = X0a + Y0a, add0b = X0b + Y0b;
  float add1a = X1a + Y1a, add1b = X1b + Y1b;
  float mul0a = X0a * Y0a, mul0b = X0b * Y0b;
  float mul1a = X1a * Y1a, mul1b = X1b * Y1b;
  size_t co = ((size_t)b * 2 * C_ + c0) * N_ + p;
  *(float2*)(cat + co)                     = make_float2(add0a, add0b);
  *(float2*)(cat + co + N_)                = make_float2(add1a, add1b);
  *(float2*)(cat + co + (size_t)C_ * N_)   = make_float2(mul0a, mul0b);
  *(float2*)(cat + co + (size_t)(C_+1)*N_) = make_float2(mul1a, mul1b);
  float fa0 = g2[c0]   * rsqrtf(v2[c0]   + EPS_), ga0 = b2[c0]   - m2[c0]   * fa0;
  float fa1 = g2[c0+1] * rsqrtf(v2[c0+1] + EPS_), ga1 = b2[c0+1] - m2[c0+1] * fa1;
  float fm0 = g2[C_+c0]   * rsqrtf(v2[C_+c0]   + EPS_), gm0 = b2[C_+c0]   - m2[C_+c0]   * fm0;
  float fm1 = g2[C_+c0+1] * rsqrtf(v2[C_+c0+1] + EPS_), gm1 = b2[C_+c0+1] - m2[C_+c0+1] * fm1;
  float* fb = fin + (size_t)b * finStride;
  size_t fo = (size_t)c0 * N_ + p;
  *(float2*)(fb + fo)                     = make_float2(add0a*fa0+ga0, add0b*fa0+ga0);
  *(float2*)(fb + fo + N_)                = make_float2(add1a*fa1+ga1, add1b*fa1+ga1);
  *(float2*)(fb + fo + (size_t)C_ * N_)   = make_float2(mul0a*fm0+gm0, mul0b*fm0+gm0);
  *(float2*)(fb + fo + (size_t)(C_+1)*N_) = make_float2(mul1a*fm1+gm1, mul1b*fm1+gm1);
}

// ------ f-branch 3x3 conv partial (64-cin half), 2 couts + 2 px -----------
// grid (18, C_, 2*B_), block 64. z: b = z&1, half = z>>1.
__global__ __launch_bounds__(64) void k_fconvs(
    const float* __restrict__ in, size_t inStride,
    const float* __restrict__ w,
    float* __restrict__ pout) {
  int p = blockIdx.x * 128 + threadIdx.x * 2;
  int c0 = blockIdx.y * 2;
  int z = blockIdx.z;
  int b = z & 1, half = z >> 1;
  int yy = p / W_, x0 = p % W_;
  const float* ib = in + (size_t)b * inStride;
  const float* w0r = w + (size_t)c0 * (2 * C_) * 9;
  const float* w1r = w0r + (size_t)(2 * C_) * 9;
  float a00 = 0.f, a01 = 0.f, a10 = 0.f, a11 = 0.f;
  int ci0 = half * C_;
  for (int ci = ci0; ci < ci0 + C_; ++ci) {
    const float* ip = ib + ci * N_;
    const float* wp0 = w0r + ci * 9;
    const float* wp1 = w1r + ci * 9;
#pragma unroll
    for (int ky = 0; ky < 3; ++ky) {
      int iyy = yy + ky - 1;
      if ((unsigned)iyy >= (unsigned)H_) continue;
      const float* rp = ip + iyy * W_;
      float2 mid = *(const float2*)(rp + x0);
      float vL = (x0 > 0) ? rp[x0 - 1] : 0.f;
      float vR = (x0 + 2 < W_) ? rp[x0 + 2] : 0.f;
      float u0 = wp0[ky*3], u1 = wp0[ky*3+1], u2 = wp0[ky*3+2];
      float t0 = wp1[ky*3], t1 = wp1[ky*3+1], t2 = wp1[ky*3+2];
      a00 += vL*u0 + mid.x*u1 + mid.y*u2;
      a01 += mid.x*u0 + mid.y*u1 + vR*u2;
      a10 += vL*t0 + mid.x*t1 + mid.y*t2;
      a11 += mid.x*t0 + mid.y*t1 + vR*t2;
    }
  }
  size_t o = (size_t)(half * 2 + b) * S_ + (size_t)c0 * N_ + p;
  *(float2*)(pout + o)      = make_float2(a00, a01);
  *(float2*)(pout + o + N_) = make_float2(a10, a11);
}

// ------ combine halves + bn + relu, float4 --------------------------------
// grid 576, block 256.
__global__ void k_comb(const float* __restrict__ pbase,
                       const float* __restrict__ g, const float* __restrict__ b2,
                       const float* __restrict__ m, const float* __restrict__ v,
                       float* __restrict__ out, size_t outStride) {
  int t = blockIdx.x * 256 + threadIdx.x;
  int p4 = t * 4;
  int n = p4 % N_;
  int c = (p4 / N_) % (2 * C_);
  int b = p4 / (2 * C_ * N_);
  size_t off = (size_t)b * S_ + (size_t)c * N_ + n;
  float4 a = *(const float4*)(pbase + off);
  float4 d = *(const float4*)(pbase + 2 * S_ + off);
  float s  = g[c] * rsqrtf(v[c] + EPS_);
  float sh = b2[c] - m[c] * s;
  float4 r;
  r.x = fmaxf((a.x + d.x) * s + sh, 0.f);
  r.y = fmaxf((a.y + d.y) * s + sh, 0.f);
  r.z = fmaxf((a.z + d.z) * s + sh, 0.f);
  r.w = fmaxf((a.w + d.w) * s + sh, 0.f);
  *(float4*)(out + (size_t)b * outStride + (size_t)c * N_ + n) = r;
}

// -------- final 1x1 conv + bias + cat add, 2 px/thread --------------------
// grid (18, 2C, B), block 64. f2 image b at f2 + b*fStride.
__global__ __launch_bounds__(64) void k_final2(
    const float* __restrict__ f2, size_t fStride,
    const float* __restrict__ cat,
    const float* __restrict__ w, const float* __restrict__ fb,
    float* __restrict__ out) {
  int p = blockIdx.x * 128 + threadIdx.x * 2;
  int c = blockIdx.y, b = blockIdx.z;
  const float* fr = f2 + (size_t)b * fStride;
  const float* wr = w + (size_t)c * 2 * C_;
  float a0 = fb[c], a1 = a0;
  for (int j = 0; j < 2 * C_; ++j) {
    float2 fv = *(const float2*)(fr + (size_t)j * N_ + p);
    float wv = wr[j];
    a0 += wv * fv.x; a1 += wv * fv.y;
  }
  size_t o = ((size_t)b * 2 * C_ + c) * N_ + p;
  float2 cv = *(const float2*)(cat + o);
  *(float2*)(out + o) = make_float2(a0 + cv.x, a1 + cv.y);
}

extern "C" void kernel_launch(void* const* d_in, const int* in_sizes, int n_in,
                              void* d_out, int out_size, void* d_ws, size_t ws_size,
                              hipStream_t stream) {
  const float* x       = (const float*)d_in[0];
  const float* y       = (const float*)d_in[1];
  const float* pconv_w = (const float*)d_in[2];
  const float* pconv_b = (const float*)d_in[3];
  const float* bnd_g = (const float*)d_in[4];
  const float* bnd_b = (const float*)d_in[5];
  const float* bnd_m = (const float*)d_in[6];
  const float* bnd_v = (const float*)d_in[7];
  const float* lnx_g = (const float*)d_in[8];
  const float* lnx_b = (const float*)d_in[9];
  const float* lny_g = (const float*)d_in[10];
  const float* lny_b = (const float*)d_in[11];
  const float* lnz_g = (const float*)d_in[12];
  const float* lnz_b = (const float*)d_in[13];
  const float* k_w   = (const float*)d_in[14];
  const float* k_b   = (const float*)d_in[15];
  const float* qv_w  = (const float*)d_in[16];
  const float* qv_b  = (const float*)d_in[17];
  const float* proj_w = (const float*)d_in[18];
  const float* proj_b = (const float*)d_in[19];
  const float* c2w1  = (const float*)d_in[20];
  const float* c2b1  = (const float*)d_in[21];
  const float* c2bn1_g = (const float*)d_in[22];
  const float* c2bn1_b = (const float*)d_in[23];
  const float* c2bn1_m = (const float*)d_in[24];
  const float* c2bn1_v = (const float*)d_in[25];
  const float* c2w2  = (const float*)d_in[26];
  const float* c2b2  = (const float*)d_in[27];
  const float* c2bn2_g = (const float*)d_in[28];
  const float* c2bn2_b = (const float*)d_in[29];
  const float* c2bn2_m = (const float*)d_in[30];
  const float* c2bn2_v = (const float*)d_in[31];
  const float* bn2_g = (const float*)d_in[32];
  const float* bn2_b = (const float*)d_in[33];
  const float* bn2_m = (const float*)d_in[34];
  const float* bn2_v = (const float*)d_in[35];
  const float* f1w   = (const float*)d_in[36];
  const float* fbn1_g = (const float*)d_in[37];
  const float* fbn1_b = (const float*)d_in[38];
  const float* fbn1_m = (const float*)d_in[39];
  const float* fbn1_v = (const float*)d_in[40];
  const float* f2w   = (const float*)d_in[41];
  const float* fbn2_g = (const float*)d_in[42];
  const float* fbn2_b = (const float*)d_in[43];
  const float* fbn2_m = (const float*)d_in[44];
  const float* fbn2_v = (const float*)d_in[45];
  const float* f3w   = (const float*)d_in[46];
  const float* f3b   = (const float*)d_in[47];

  // 8-slot workspace plan:
  //   A: k_pre -> xl(1) yl(2) zl(3)
  //   B: qvk -> xq(4) xv(5) yq(6) yv(7); kk(0)
  //   C: attn6 -> att_xo(1) att_yo(2)
  //   D: proj -> xo(3,4)  [layout z*C*N, z = branch*B+b; branch stride = S_]
  //   E: convp -> tmp(5,6) [same z layout]
  //   F: conv2cat (reads tmp; resid 3,4) -> cat(1,2), fin -> 0 and 7
  //   G1: fconvs f1 partials -> 3,4,5,6 ; G2: comb -> 0,7
  //   G3: fconvs f2 partials -> 3,4,5,6 ; G4: comb -> 0,7
  //   H: final reads (0,7) + cat(1,2)
  float* ws = (float*)d_ws;
  float* sl0 = ws + 0 * S_;
  float* sl1 = ws + 1 * S_;
  float* sl2 = ws + 2 * S_;
  float* sl3 = ws + 3 * S_;
  float* sl4 = ws + 4 * S_;
  float* sl5 = ws + 5 * S_;

  // A. fused pconv + bn + ln
  k_pre<<<B_ * N_, 64, 0, stream>>>(x, y, pconv_w, pconv_b,
                                    bnd_g, bnd_b, bnd_m, bnd_v,
                                    lnx_g, lnx_b, lny_g, lny_b, lnz_g, lnz_b,
                                    sl1, sl2, sl3);
  // B. fused qv + kproj
  {
    dim3 g(2304, 1, 3);
    k_qvk<<<g, 256, 0, stream>>>(sl1, sl3, qv_w, qv_b, k_w, k_b, sl4, sl5, sl0);
  }
  // C. attention v6b -> att_xo(1), att_yo(2)
  {
    dim3 g(N_ / 128, B_ * NH_);
    k_attn6<<<g, 1024, 0, stream>>>(sl4, sl5, ws + 6 * S_, ws + 7 * S_, sl0,
                                    sl1, sl2);
  }
  // D. proj batched -> xo(3,4)
  {
    dim3 g(18, C_, 2 * B_);
    k_proj2<<<g, 64, 0, stream>>>(sl1, x, y, bnd_g, bnd_b, bnd_m, bnd_v,
                                  proj_w, proj_b, sl3);
  }
  // E. conv1, branch-split -> tmp(5,6)
  {
    dim3 g(18, C_ / 2, 2 * B_);
    k_convp<<<g, 64, 0, stream>>>(sl3, c2w1, c2b1,
        c2bn1_g, c2bn1_b, c2bn1_m, c2bn1_v, sl5);
  }
  // F. conv2 + resid + cat + bn2 -> cat(1,2), fin(0 / 7)
  {
    dim3 g(18, C_ / 2, B_);
    k_conv2cat<<<g, 64, 0, stream>>>(sl5, c2w2, c2b2,
        c2bn2_g, c2bn2_b, c2bn2_m, c2bn2_v, sl3,
        bn2_g, bn2_b, bn2_m, bn2_v, sl1, sl0, 7 * S_);
  }
  // G. f-branch convs, ci-split + combine
  {
    dim3 g(18, C_, 2 * B_);
    k_fconvs<<<g, 64, 0, stream>>>(sl0, 7 * S_, f1w, sl3);
    k_comb<<<576, 256, 0, stream>>>(sl3, fbn1_g, fbn1_b, fbn1_m, fbn1_v,
                                    sl0, 7 * S_);
    k_fconvs<<<g, 64, 0, stream>>>(sl0, 7 * S_, f2w, sl3);
    k_comb<<<576, 256, 0, stream>>>(sl3, fbn2_g, fbn2_b, fbn2_m, fbn2_v,
                                    sl0, 7 * S_);
  }
  // H. final 1x1 + cat add -> fp32 out
  {
    dim3 g(18, 2 * C_, B_);
    k_final2<<<g, 64, 0, stream>>>(sl0, 7 * S_, sl1, f3w, f3b, (float*)d_out);
  }
}

// Round 11
// 690.823 us; speedup vs baseline: 1.2444x; 1.0467x over previous
//
#include <hip/hip_runtime.h>
#include <hip/hip_bf16.h>

#define B_   2
#define C_   64
#define H_   48
#define W_   48
#define N_   (H_*W_)     // 2304
#define NH_  8
#define HD_  8
#define EPS_ 1e-5f
#define S2_  0.125f      // scale^2 = 1/hd
#define LOG2E_ 1.44269504f
#define S_   ((size_t)B_ * C_ * N_)   // 294912 floats per workspace slot

__device__ __forceinline__ float wsum64(float v) {
#pragma unroll
  for (int o = 32; o > 0; o >>= 1) v += __shfl_xor(v, o, 64);
  return v;
}

__device__ __forceinline__ float ln_val(float t, float g, float b) {
  float mu  = wsum64(t) * (1.0f / 64.0f);
  float d   = t - mu;
  float var = wsum64(d * d) * (1.0f / 64.0f);
  return d * rsqrtf(var + EPS_) * g + b;
}

// ---- fused 1x1 pconv + BN + 3x LayerNorm; block = one (b,n) row ----------
// grid B*N, block 64 (lane = channel)
__global__ __launch_bounds__(64) void k_pre(
    const float* __restrict__ x, const float* __restrict__ y,
    const float* __restrict__ pw, const float* __restrict__ pb,
    const float* g, const float* bb, const float* m, const float* v,
    const float* lnxg, const float* lnxb,
    const float* lnyg, const float* lnyb,
    const float* lnzg, const float* lnzb,
    float* __restrict__ xl, float* __restrict__ yl, float* __restrict__ zl) {
  __shared__ float xs[64], ys[64];
  int row = blockIdx.x;            // b*N + n
  int c = threadIdx.x;
  int b = row / N_, n = row % N_;
  float xv = x[(size_t)(b * C_ + c) * N_ + n];
  float yv = y[(size_t)(b * C_ + c) * N_ + n];
  xs[c] = xv; ys[c] = yv;
  __syncthreads();
  const float4* wr  = (const float4*)(pw + (size_t)c * 2 * C_);
  const float4* xs4 = (const float4*)xs;
  const float4* ys4 = (const float4*)ys;
  float acc = pb[c];
#pragma unroll
  for (int t = 0; t < 16; ++t) {
    float4 a = xs4[t], wv = wr[t];
    acc += a.x * wv.x + a.y * wv.y + a.z * wv.z + a.w * wv.w;
  }
#pragma unroll
  for (int t = 0; t < 16; ++t) {
    float4 a = ys4[t], wv = wr[16 + t];
    acc += a.x * wv.x + a.y * wv.y + a.z * wv.z + a.w * wv.w;
  }
  float s  = g[c] * rsqrtf(v[c] + EPS_);
  float sh = bb[c] - m[c] * s;
  float tx = xv * s + sh;
  xl[(size_t)row * C_ + c] = ln_val(tx, lnxg[c], lnxb[c]);
  float ty = yv * s + sh;
  yl[(size_t)row * C_ + c] = ln_val(ty, lnyg[c], lnyb[c]);
  float tz = acc * s + sh;
  zl[(size_t)row * C_ + c] = ln_val(tz, lnzg[c], lnzb[c]);
}

// ------------- fused qv (both branches) + k projection --------------------
// grid (2304, 1, 3), block 256. z=0,1: qv branch z; z=2: kproj (first 1152 blocks)
__global__ void k_qvk(const float* __restrict__ lnb, const float* __restrict__ zl,
                      const float* __restrict__ qvw, const float* __restrict__ qvb,
                      const float* __restrict__ kw, const float* __restrict__ kb,
                      float* __restrict__ qb, float* __restrict__ vb,
                      float* __restrict__ kk) {
  int z = blockIdx.z;
  if (z < 2) {
    int idx = blockIdx.x * 256 + threadIdx.x;   // B*N*128
    int j = idx & 127;
    int row = idx >> 7;
    int b = row / N_, n = row % N_;
    const float4* ir = (const float4*)(lnb + z * S_ + (size_t)row * C_);
    const float4* wr = (const float4*)(qvw + (size_t)j * C_);
    float acc = qvb[j];
#pragma unroll
    for (int t = 0; t < 16; ++t) {
      float4 a = ir[t], wv = wr[t];
      acc += a.x * wv.x + a.y * wv.y + a.z * wv.z + a.w * wv.w;
    }
    int jj = j & 63;
    int h = jj >> 3, d = jj & 7;
    float* dst = ((j < C_) ? qb : vb) + z * 2 * S_;
    dst[((size_t)(b * NH_ + h) * N_ + n) * HD_ + d] = acc;
  } else {
    if (blockIdx.x >= 1152) return;
    int idx = blockIdx.x * 256 + threadIdx.x;   // B*N*64
    int j = idx & 63;
    int row = idx >> 6;
    int b = row / N_, n = row % N_;
    const float4* ir = (const float4*)(zl + (size_t)row * C_);
    const float4* wr = (const float4*)(kw + (size_t)j * C_);
    float acc = kb[j];
#pragma unroll
    for (int t = 0; t < 16; ++t) {
      float4 a = ir[t], wv = wr[t];
      acc += a.x * wv.x + a.y * wv.y + a.z * wv.z + a.w * wv.w;
    }
    int h = j >> 3, d = j & 7;
    kk[((size_t)(b * NH_ + h) * N_ + n) * HD_ + d] = acc;
  }
}

// ---------------- attention v7: attn5 structure + 2-key ILP ---------------
// grid (36, B*NH), block 1024 (16 waves x 144-key strips); no-max softmax;
// two independent key chains per iteration for memory-level parallelism.
#define AW 16
__global__ __launch_bounds__(1024, 8) void k_attn7(
    const float* __restrict__ xq, const float* __restrict__ xv,
    const float* __restrict__ yq, const float* __restrict__ yv,
    const float* __restrict__ kk,
    float* __restrict__ outx, float* __restrict__ outy) {
  __shared__ float pl[AW][64];
  __shared__ float pbuf[AW][8][64];
  int bh  = blockIdx.y;
  int qt  = blockIdx.x;
  int tid = threadIdx.x;
  int lane = tid & 63;
  int wave = __builtin_amdgcn_readfirstlane(tid >> 6);   // uniform -> scalar addrs
  int q = qt * 64 + lane;
  size_t base = (size_t)bh * N_ * HD_;

  float4 qx0 = ((const float4*)(xq + base + (size_t)q * HD_))[0];
  float4 qx1 = ((const float4*)(xq + base + (size_t)q * HD_))[1];
  float4 qy0 = ((const float4*)(yq + base + (size_t)q * HD_))[0];
  float4 qy1 = ((const float4*)(yq + base + (size_t)q * HD_))[1];
  const float fs = S2_ * LOG2E_;   // fold scale^2*log2e -> exp2 domain
  qx0.x *= fs; qx0.y *= fs; qx0.z *= fs; qx0.w *= fs;
  qx1.x *= fs; qx1.y *= fs; qx1.z *= fs; qx1.w *= fs;

  float l = 0.f;
  float ax[8] = {0,0,0,0,0,0,0,0};
  float ay[8] = {0,0,0,0,0,0,0,0};

  const float4* kp = (const float4*)(kk + base);
  const float4* xp = (const float4*)(xv + base);
  const float4* yp = (const float4*)(yv + base);
  int k0 = wave * (N_ / AW);
  for (int mi = k0; mi < k0 + N_ / AW; mi += 2) {
    // issue both keys' loads up front (independent chains)
    float4 kaA  = kp[2 * mi],     kbA = kp[2 * mi + 1];
    float4 kaB  = kp[2 * mi + 2], kbB = kp[2 * mi + 3];
    float4 xaA = xp[2 * mi],     xbA = xp[2 * mi + 1];
    float4 xaB = xp[2 * mi + 2], xbB = xp[2 * mi + 3];
    float4 yaA = yp[2 * mi],     ybA = yp[2 * mi + 1];
    float4 yaB = yp[2 * mi + 2], ybB = yp[2 * mi + 3];
    float s1A = qx0.x*kaA.x + qx0.y*kaA.y + qx0.z*kaA.z + qx0.w*kaA.w
              + qx1.x*kbA.x + qx1.y*kbA.y + qx1.z*kbA.z + qx1.w*kbA.w;
    float s2A = qy0.x*kaA.x + qy0.y*kaA.y + qy0.z*kaA.z + qy0.w*kaA.w
              + qy1.x*kbA.x + qy1.y*kbA.y + qy1.z*kbA.z + qy1.w*kbA.w;
    float s1B = qx0.x*kaB.x + qx0.y*kaB.y + qx0.z*kaB.z + qx0.w*kaB.w
              + qx1.x*kbB.x + qx1.y*kbB.y + qx1.z*kbB.z + qx1.w*kbB.w;
    float s2B = qy0.x*kaB.x + qy0.y*kaB.y + qy0.z*kaB.z + qy0.w*kaB.w
              + qy1.x*kbB.x + qy1.y*kbB.y + qy1.z*kbB.z + qy1.w*kbB.w;
    float pA = exp2f(s1A * s2A);
    float pB = exp2f(s1B * s2B);
    l += pA + pB;
    ax[0] += pA*xaA.x + pB*xaB.x;  ax[1] += pA*xaA.y + pB*xaB.y;
    ax[2] += pA*xaA.z + pB*xaB.z;  ax[3] += pA*xaA.w + pB*xaB.w;
    ax[4] += pA*xbA.x + pB*xbB.x;  ax[5] += pA*xbA.y + pB*xbB.y;
    ax[6] += pA*xbA.z + pB*xbB.z;  ax[7] += pA*xbA.w + pB*xbB.w;
    ay[0] += pA*yaA.x + pB*yaB.x;  ay[1] += pA*yaA.y + pB*yaB.y;
    ay[2] += pA*yaA.z + pB*yaB.z;  ay[3] += pA*yaA.w + pB*yaB.w;
    ay[4] += pA*ybA.x + pB*ybB.x;  ay[5] += pA*ybA.y + pB*ybB.y;
    ay[6] += pA*ybA.z + pB*ybB.z;  ay[7] += pA*ybA.w + pB*ybB.w;
  }
  pl[wave][lane] = l;
#pragma unroll
  for (int d = 0; d < 8; ++d) pbuf[wave][d][lane] = ax[d];
  __syncthreads();
  float Linv = 0.f;
  int b = bh / NH_, h = bh % NH_;
  if (tid < 64) {
    float L = 0.f;
#pragma unroll
    for (int w = 0; w < AW; ++w) L += pl[w][lane];
    Linv = 1.f / L;
    float A[8] = {0,0,0,0,0,0,0,0};
#pragma unroll
    for (int w = 0; w < AW; ++w)
#pragma unroll
      for (int d = 0; d < 8; ++d) A[d] += pbuf[w][d][lane];
    float* o = outx + ((size_t)(b * N_ + q)) * C_ + h * HD_;
#pragma unroll
    for (int d = 0; d < 8; ++d) o[d] = A[d] * Linv;
  }
  __syncthreads();
#pragma unroll
  for (int d = 0; d < 8; ++d) pbuf[wave][d][lane] = ay[d];
  __syncthreads();
  if (tid < 64) {
    float A[8] = {0,0,0,0,0,0,0,0};
#pragma unroll
    for (int w = 0; w < AW; ++w)
#pragma unroll
      for (int d = 0; d < 8; ++d) A[d] += pbuf[w][d][lane];
    float* o = outy + ((size_t)(b * N_ + q)) * C_ + h * HD_;
#pragma unroll
    for (int d = 0; d < 8; ++d) o[d] = A[d] * Linv;
  }
}

// -------- proj + recomputed-BN residual, 2 px/thread, batched branches ----
// grid (18, C_, 2*B_), block 64. out layout z*C*N, z = branch*B_ + b.
__global__ __launch_bounds__(64) void k_proj2(
    const float* __restrict__ attbase,
    const float* __restrict__ x, const float* __restrict__ y,
    const float* bg, const float* bb2, const float* bm, const float* bv,
    const float* __restrict__ pw, const float* __restrict__ pbias,
    float* __restrict__ outbase) {
  int p = blockIdx.x * 128 + threadIdx.x * 2;
  int c = blockIdx.y;
  int z = blockIdx.z;                 // branch*B_ + b
  int branch = z >> 1, b = z & 1;
  const float* att = attbase + branch * S_ + (size_t)b * N_ * C_;
  const float4* wr = (const float4*)(pw + (size_t)c * C_);
  float bias = pbias[c];
  float acc[2];
#pragma unroll
  for (int i = 0; i < 2; ++i) {
    const float4* ar = (const float4*)(att + (size_t)(p + i) * C_);
    float a = bias;
#pragma unroll
    for (int t = 0; t < 16; ++t) {
      float4 av = ar[t], wv = wr[t];
      a += av.x * wv.x + av.y * wv.y + av.z * wv.z + av.w * wv.w;
    }
    acc[i] = a;
  }
  float s  = bg[c] * rsqrtf(bv[c] + EPS_);
  float sh = bb2[c] - bm[c] * s;
  const float* xin = branch ? y : x;
  float2 r = *(const float2*)(xin + ((size_t)b * C_ + c) * N_ + p);
  size_t o = ((size_t)z * C_ + c) * N_ + p;
  *(float2*)(outbase + o) = make_float2(acc[0] + r.x * s + sh,
                                        acc[1] + r.y * s + sh);
}

// ------ conv1 of conv2_block: one branch per z, 2 couts + 2 px ------------
// grid (18, C_/2, 2*B_), block 64. z = branch*B_ + b (layout z*C*N).
__global__ __launch_bounds__(64) void k_convp(
    const float* __restrict__ in, const float* __restrict__ w,
    const float* __restrict__ cb,
    const float* __restrict__ bg, const float* __restrict__ bbeta,
    const float* __restrict__ bm, const float* __restrict__ bv,
    float* __restrict__ out) {
  int p = blockIdx.x * 128 + threadIdx.x * 2;
  int c0 = blockIdx.y * 2;
  int z = blockIdx.z;
  int yy = p / W_, x0 = p % W_;
  const float* ib = in + (size_t)z * C_ * N_;
  const float* w0r = w + (size_t)c0 * C_ * 9;
  const float* w1r = w0r + (size_t)C_ * 9;
  float bias0 = cb[c0], bias1 = cb[c0 + 1];
  float a00 = bias0, a01 = bias0, a10 = bias1, a11 = bias1;
#pragma unroll 2
  for (int ci = 0; ci < C_; ++ci) {
    const float* ip = ib + ci * N_;
    const float* wp0 = w0r + ci * 9;
    const float* wp1 = w1r + ci * 9;
#pragma unroll
    for (int ky = 0; ky < 3; ++ky) {
      int iyy = yy + ky - 1;
      if ((unsigned)iyy >= (unsigned)H_) continue;
      const float* rp = ip + iyy * W_;
      float2 mid = *(const float2*)(rp + x0);
      float vL = (x0 > 0) ? rp[x0 - 1] : 0.f;
      float vR = (x0 + 2 < W_) ? rp[x0 + 2] : 0.f;
      float u0 = wp0[ky*3], u1 = wp0[ky*3+1], u2 = wp0[ky*3+2];
      float t0 = wp1[ky*3], t1 = wp1[ky*3+1], t2 = wp1[ky*3+2];
      a00 += vL*u0 + mid.x*u1 + mid.y*u2;
      a01 += mid.x*u0 + mid.y*u1 + vR*u2;
      a10 += vL*t0 + mid.x*t1 + mid.y*t2;
      a11 += mid.x*t0 + mid.y*t1 + vR*t2;
    }
  }
  float s0 = bg[c0] * rsqrtf(bv[c0] + EPS_);
  float sh0 = bbeta[c0] - bm[c0] * s0;
  float s1 = bg[c0+1] * rsqrtf(bv[c0+1] + EPS_);
  float sh1 = bbeta[c0+1] - bm[c0+1] * s1;
  size_t o = (size_t)z * C_ * N_ + (size_t)c0 * N_ + p;
  *(float2*)(out + o)      = make_float2(fmaxf(a00*s0+sh0,0.f), fmaxf(a01*s0+sh0,0.f));
  *(float2*)(out + o + N_) = make_float2(fmaxf(a10*s1+sh1,0.f), fmaxf(a11*s1+sh1,0.f));
}

// ------ conv2 + bn + relu + residual + cat + bn2, fused epilogue ----------
// grid (18, C_/2, B_), block 64. in/resid layout [branch][b][C][N], branch
// stride S_. fin image b at fin + b*finStride.
__global__ __launch_bounds__(64) void k_conv2cat(
    const float* __restrict__ in, const float* __restrict__ w,
    const float* __restrict__ cb,
    const float* __restrict__ bg, const float* __restrict__ bbeta,
    const float* __restrict__ bm, const float* __restrict__ bv,
    const float* __restrict__ resid,
    const float* __restrict__ g2, const float* __restrict__ b2,
    const float* __restrict__ m2, const float* __restrict__ v2,
    float* __restrict__ cat, float* __restrict__ fin, size_t finStride) {
  int p = blockIdx.x * 128 + threadIdx.x * 2;
  int c0 = blockIdx.y * 2;
  int b = blockIdx.z;
  int yy = p / W_, x0 = p % W_;
  const float* ix  = in + (size_t)b * C_ * N_;
  const float* iy2 = in + S_ + (size_t)b * C_ * N_;
  const float* w0r = w + (size_t)c0 * C_ * 9;
  const float* w1r = w0r + (size_t)C_ * 9;
  float bias0 = cb[c0], bias1 = cb[c0 + 1];
  float xa0 = bias0, xa1 = bias0, xb0 = bias1, xb1 = bias1;
  float ya0 = bias0, ya1 = bias0, yb0 = bias1, yb1 = bias1;
  for (int ci = 0; ci < C_; ++ci) {
    const float* ipx = ix + ci * N_;
    const float* ipy = iy2 + ci * N_;
    const float* wp0 = w0r + ci * 9;
    const float* wp1 = w1r + ci * 9;
#pragma unroll
    for (int ky = 0; ky < 3; ++ky) {
      int iyy = yy + ky - 1;
      if ((unsigned)iyy >= (unsigned)H_) continue;
      const float* rpx = ipx + iyy * W_;
      const float* rpy = ipy + iyy * W_;
      float2 mx = *(const float2*)(rpx + x0);
      float lx = (x0 > 0) ? rpx[x0 - 1] : 0.f;
      float rx = (x0 + 2 < W_) ? rpx[x0 + 2] : 0.f;
      float2 my = *(const float2*)(rpy + x0);
      float ly = (x0 > 0) ? rpy[x0 - 1] : 0.f;
      float ry = (x0 + 2 < W_) ? rpy[x0 + 2] : 0.f;
      float u0 = wp0[ky*3], u1 = wp0[ky*3+1], u2 = wp0[ky*3+2];
      float t0 = wp1[ky*3], t1 = wp1[ky*3+1], t2 = wp1[ky*3+2];
      xa0 += lx*u0 + mx.x*u1 + mx.y*u2;
      xa1 += mx.x*u0 + mx.y*u1 + rx*u2;
      xb0 += lx*t0 + mx.x*t1 + mx.y*t2;
      xb1 += mx.x*t0 + mx.y*t1 + rx*t2;
      ya0 += ly*u0 + my.x*u1 + my.y*u2;
      ya1 += my.x*u0 + my.y*u1 + ry*u2;
      yb0 += ly*t0 + my.x*t1 + my.y*t2;
      yb1 += my.x*t0 + my.y*t1 + ry*t2;
    }
  }
  float s0 = bg[c0] * rsqrtf(bv[c0] + EPS_);
  float sh0 = bbeta[c0] - bm[c0] * s0;
  float s1 = bg[c0+1] * rsqrtf(bv[c0+1] + EPS_);
  float sh1 = bbeta[c0+1] - bm[c0+1] * s1;
  float X0a = fmaxf(xa0*s0+sh0, 0.f), X0b = fmaxf(xa1*s0+sh0, 0.f);
  float X1a = fmaxf(xb0*s1+sh1, 0.f), X1b = fmaxf(xb1*s1+sh1, 0.f);
  float Y0a = fmaxf(ya0*s0+sh0, 0.f), Y0b = fmaxf(ya1*s0+sh0, 0.f);
  float Y1a = fmaxf(yb0*s1+sh1, 0.f), Y1b = fmaxf(yb1*s1+sh1, 0.f);
  size_t ro = ((size_t)b * C_ + c0) * N_ + p;
  float2 rX0 = *(const float2*)(resid + ro);
  float2 rX1 = *(const float2*)(resid + ro + N_);
  float2 rY0 = *(const float2*)(resid + S_ + ro);        // branch stride = S_
  float2 rY1 = *(const float2*)(resid + S_ + ro + N_);
  X0a += rX0.x; X0b += rX0.y; X1a += rX1.x; X1b += rX1.y;
  Y0a += rY0.x; Y0b += rY0.y; Y1a += rY1.x; Y1b += rY1.y;
  float add0a = X0a + Y0a, add0b = X0b + Y0b;
  float add1a = X1a + Y1a, add1b = X1b + Y1b;
  float mul0a = X0a * Y0a, mul0b = X0b * Y0b;
  float mul1a = X1a * Y1a, mul1b = X1b * Y1b;
  size_t co = ((size_t)b * 2 * C_ + c0) * N_ + p;
  *(float2*)(cat + co)                     = make_float2(add0a, add0b);
  *(float2*)(cat + co + N_)                = make_float2(add1a, add1b);
  *(float2*)(cat + co + (size_t)C_ * N_)   = make_float2(mul0a, mul0b);
  *(float2*)(cat + co + (size_t)(C_+1)*N_) = make_float2(mul1a, mul1b);
  float fa0 = g2[c0]   * rsqrtf(v2[c0]   + EPS_), ga0 = b2[c0]   - m2[c0]   * fa0;
  float fa1 = g2[c0+1] * rsqrtf(v2[c0+1] + EPS_), ga1 = b2[c0+1] - m2[c0+1] * fa1;
  float fm0 = g2[C_+c0]   * rsqrtf(v2[C_+c0]   + EPS_), gm0 = b2[C_+c0]   - m2[C_+c0]   * fm0;
  float fm1 = g2[C_+c0+1] * rsqrtf(v2[C_+c0+1] + EPS_), gm1 = b2[C_+c0+1] - m2[C_+c0+1] * fm1;
  float* fb = fin + (size_t)b * finStride;
  size_t fo = (size_t)c0 * N_ + p;
  *(float2*)(fb + fo)                     = make_float2(add0a*fa0+ga0, add0b*fa0+ga0);
  *(float2*)(fb + fo + N_)                = make_float2(add1a*fa1+ga1, add1b*fa1+ga1);
  *(float2*)(fb + fo + (size_t)C_ * N_)   = make_float2(mul0a*fm0+gm0, mul0b*fm0+gm0);
  *(float2*)(fb + fo + (size_t)(C_+1)*N_) = make_float2(mul1a*fm1+gm1, mul1b*fm1+gm1);
}

// ------ f-branch 3x3 conv partial (64-cin half), 2 couts + 2 px -----------
// grid (18, C_, 2*B_), block 64. z: b = z&1, half = z>>1.
__global__ __launch_bounds__(64) void k_fconvs(
    const float* __restrict__ in, size_t inStride,
    const float* __restrict__ w,
    float* __restrict__ pout) {
  int p = blockIdx.x * 128 + threadIdx.x * 2;
  int c0 = blockIdx.y * 2;
  int z = blockIdx.z;
  int b = z & 1, half = z >> 1;
  int yy = p / W_, x0 = p % W_;
  const float* ib = in + (size_t)b * inStride;
  const float* w0r = w + (size_t)c0 * (2 * C_) * 9;
  const float* w1r = w0r + (size_t)(2 * C_) * 9;
  float a00 = 0.f, a01 = 0.f, a10 = 0.f, a11 = 0.f;
  int ci0 = half * C_;
#pragma unroll 2
  for (int ci = ci0; ci < ci0 + C_; ++ci) {
    const float* ip = ib + ci * N_;
    const float* wp0 = w0r + ci * 9;
    const float* wp1 = w1r + ci * 9;
#pragma unroll
    for (int ky = 0; ky < 3; ++ky) {
      int iyy = yy + ky - 1;
      if ((unsigned)iyy >= (unsigned)H_) continue;
      const float* rp = ip + iyy * W_;
      float2 mid = *(const float2*)(rp + x0);
      float vL = (x0 > 0) ? rp[x0 - 1] : 0.f;
      float vR = (x0 + 2 < W_) ? rp[x0 + 2] : 0.f;
      float u0 = wp0[ky*3], u1 = wp0[ky*3+1], u2 = wp0[ky*3+2];
      float t0 = wp1[ky*3], t1 = wp1[ky*3+1], t2 = wp1[ky*3+2];
      a00 += vL*u0 + mid.x*u1 + mid.y*u2;
      a01 += mid.x*u0 + mid.y*u1 + vR*u2;
      a10 += vL*t0 + mid.x*t1 + mid.y*t2;
      a11 += mid.x*t0 + mid.y*t1 + vR*t2;
    }
  }
  size_t o = (size_t)(half * 2 + b) * S_ + (size_t)c0 * N_ + p;
  *(float2*)(pout + o)      = make_float2(a00, a01);
  *(float2*)(pout + o + N_) = make_float2(a10, a11);
}

// ------ combine halves + bn + relu, float4 --------------------------------
// grid 576, block 256.
__global__ void k_comb(const float* __restrict__ pbase,
                       const float* __restrict__ g, const float* __restrict__ b2,
                       const float* __restrict__ m, const float* __restrict__ v,
                       float* __restrict__ out, size_t outStride) {
  int t = blockIdx.x * 256 + threadIdx.x;
  int p4 = t * 4;
  int n = p4 % N_;
  int c = (p4 / N_) % (2 * C_);
  int b = p4 / (2 * C_ * N_);
  size_t off = (size_t)b * S_ + (size_t)c * N_ + n;
  float4 a = *(const float4*)(pbase + off);
  float4 d = *(const float4*)(pbase + 2 * S_ + off);
  float s  = g[c] * rsqrtf(v[c] + EPS_);
  float sh = b2[c] - m[c] * s;
  float4 r;
  r.x = fmaxf((a.x + d.x) * s + sh, 0.f);
  r.y = fmaxf((a.y + d.y) * s + sh, 0.f);
  r.z = fmaxf((a.z + d.z) * s + sh, 0.f);
  r.w = fmaxf((a.w + d.w) * s + sh, 0.f);
  *(float4*)(out + (size_t)b * outStride + (size_t)c * N_ + n) = r;
}

// -------- final 1x1 conv + bias + cat add, 2 px/thread --------------------
// grid (18, 2C, B), block 64. f2 image b at f2 + b*fStride.
__global__ __launch_bounds__(64) void k_final2(
    const float* __restrict__ f2, size_t fStride,
    const float* __restrict__ cat,
    const float* __restrict__ w, const float* __restrict__ fb,
    float* __restrict__ out) {
  int p = blockIdx.x * 128 + threadIdx.x * 2;
  int c = blockIdx.y, b = blockIdx.z;
  const float* fr = f2 + (size_t)b * fStride;
  const float* wr = w + (size_t)c * 2 * C_;
  float a0 = fb[c], a1 = a0;
  for (int j = 0; j < 2 * C_; ++j) {
    float2 fv = *(const float2*)(fr + (size_t)j * N_ + p);
    float wv = wr[j];
    a0 += wv * fv.x; a1 += wv * fv.y;
  }
  size_t o = ((size_t)b * 2 * C_ + c) * N_ + p;
  float2 cv = *(const float2*)(cat + o);
  *(float2*)(out + o) = make_float2(a0 + cv.x, a1 + cv.y);
}

extern "C" void kernel_launch(void* const* d_in, const int* in_sizes, int n_in,
                              void* d_out, int out_size, void* d_ws, size_t ws_size,
                              hipStream_t stream) {
  const float* x       = (const float*)d_in[0];
  const float* y       = (const float*)d_in[1];
  const float* pconv_w = (const float*)d_in[2];
  const float* pconv_b = (const float*)d_in[3];
  const float* bnd_g = (const float*)d_in[4];
  const float* bnd_b = (const float*)d_in[5];
  const float* bnd_m = (const float*)d_in[6];
  const float* bnd_v = (const float*)d_in[7];
  const float* lnx_g = (const float*)d_in[8];
  const float* lnx_b = (const float*)d_in[9];
  const float* lny_g = (const float*)d_in[10];
  const float* lny_b = (const float*)d_in[11];
  const float* lnz_g = (const float*)d_in[12];
  const float* lnz_b = (const float*)d_in[13];
  const float* k_w   = (const float*)d_in[14];
  const float* k_b   = (const float*)d_in[15];
  const float* qv_w  = (const float*)d_in[16];
  const float* qv_b  = (const float*)d_in[17];
  const float* proj_w = (const float*)d_in[18];
  const float* proj_b = (const float*)d_in[19];
  const float* c2w1  = (const float*)d_in[20];
  const float* c2b1  = (const float*)d_in[21];
  const float* c2bn1_g = (const float*)d_in[22];
  const float* c2bn1_b = (const float*)d_in[23];
  const float* c2bn1_m = (const float*)d_in[24];
  const float* c2bn1_v = (const float*)d_in[25];
  const float* c2w2  = (const float*)d_in[26];
  const float* c2b2  = (const float*)d_in[27];
  const float* c2bn2_g = (const float*)d_in[28];
  const float* c2bn2_b = (const float*)d_in[29];
  const float* c2bn2_m = (const float*)d_in[30];
  const float* c2bn2_v = (const float*)d_in[31];
  const float* bn2_g = (const float*)d_in[32];
  const float* bn2_b = (const float*)d_in[33];
  const float* bn2_m = (const float*)d_in[34];
  const float* bn2_v = (const float*)d_in[35];
  const float* f1w   = (const float*)d_in[36];
  const float* fbn1_g = (const float*)d_in[37];
  const float* fbn1_b = (const float*)d_in[38];
  const float* fbn1_m = (const float*)d_in[39];
  const float* fbn1_v = (const float*)d_in[40];
  const float* f2w   = (const float*)d_in[41];
  const float* fbn2_g = (const float*)d_in[42];
  const float* fbn2_b = (const float*)d_in[43];
  const float* fbn2_m = (const float*)d_in[44];
  const float* fbn2_v = (const float*)d_in[45];
  const float* f3w   = (const float*)d_in[46];
  const float* f3b   = (const float*)d_in[47];

  // 8-slot workspace plan:
  //   A: k_pre -> xl(1) yl(2) zl(3)
  //   B: qvk -> xq(4) xv(5) yq(6) yv(7); kk(0)
  //   C: attn7 -> att_xo(1) att_yo(2)
  //   D: proj -> xo(3,4)  [layout z*C*N, z = branch*B+b; branch stride = S_]
  //   E: convp -> tmp(5,6) [same z layout]
  //   F: conv2cat (reads tmp; resid 3,4) -> cat(1,2), fin -> 0 and 7
  //   G1: fconvs f1 partials -> 3,4,5,6 ; G2: comb -> 0,7
  //   G3: fconvs f2 partials -> 3,4,5,6 ; G4: comb -> 0,7
  //   H: final reads (0,7) + cat(1,2)
  float* ws = (float*)d_ws;
  float* sl0 = ws + 0 * S_;
  float* sl1 = ws + 1 * S_;
  float* sl2 = ws + 2 * S_;
  float* sl3 = ws + 3 * S_;
  float* sl4 = ws + 4 * S_;
  float* sl5 = ws + 5 * S_;

  // A. fused pconv + bn + ln
  k_pre<<<B_ * N_, 64, 0, stream>>>(x, y, pconv_w, pconv_b,
                                    bnd_g, bnd_b, bnd_m, bnd_v,
                                    lnx_g, lnx_b, lny_g, lny_b, lnz_g, lnz_b,
                                    sl1, sl2, sl3);
  // B. fused qv + kproj
  {
    dim3 g(2304, 1, 3);
    k_qvk<<<g, 256, 0, stream>>>(sl1, sl3, qv_w, qv_b, k_w, k_b, sl4, sl5, sl0);
  }
  // C. attention v7 -> att_xo(1), att_yo(2)
  {
    dim3 g(N_ / 64, B_ * NH_);
    k_attn7<<<g, 1024, 0, stream>>>(sl4, sl5, ws + 6 * S_, ws + 7 * S_, sl0,
                                    sl1, sl2);
  }
  // D. proj batched -> xo(3,4)
  {
    dim3 g(18, C_, 2 * B_);
    k_proj2<<<g, 64, 0, stream>>>(sl1, x, y, bnd_g, bnd_b, bnd_m, bnd_v,
                                  proj_w, proj_b, sl3);
  }
  // E. conv1, branch-split -> tmp(5,6)
  {
    dim3 g(18, C_ / 2, 2 * B_);
    k_convp<<<g, 64, 0, stream>>>(sl3, c2w1, c2b1,
        c2bn1_g, c2bn1_b, c2bn1_m, c2bn1_v, sl5);
  }
  // F. conv2 + resid + cat + bn2 -> cat(1,2), fin(0 / 7)
  {
    dim3 g(18, C_ / 2, B_);
    k_conv2cat<<<g, 64, 0, stream>>>(sl5, c2w2, c2b2,
        c2bn2_g, c2bn2_b, c2bn2_m, c2bn2_v, sl3,
        bn2_g, bn2_b, bn2_m, bn2_v, sl1, sl0, 7 * S_);
  }
  // G. f-branch convs, ci-split + combine
  {
    dim3 g(18, C_, 2 * B_);
    k_fconvs<<<g, 64, 0, stream>>>(sl0, 7 * S_, f1w, sl3);
    k_comb<<<576, 256, 0, stream>>>(sl3, fbn1_g, fbn1_b, fbn1_m, fbn1_v,
                                    sl0, 7 * S_);
    k_fconvs<<<g, 64, 0, stream>>>(sl0, 7 * S_, f2w, sl3);
    k_comb<<<576, 256, 0, stream>>>(sl3, fbn2_g, fbn2_b, fbn2_m, fbn2_v,
                                    sl0, 7 * S_);
  }
  // H. final 1x1 + cat add -> fp32 out
  {
    dim3 g(18, 2 * C_, B_);
    k_final2<<<g, 64, 0, stream>>>(sl0, 7 * S_, sl1, f3w, f3b, (float*)d_out);
  }
}